// Round 3
// baseline (502.061 us; speedup 1.0000x reference)
//
#include <hip/hip_runtime.h>

// ---------------------------------------------------------------------------
// AttnBlock: GroupNorm -> QKV (1x1 conv) -> 4-head attention (L=2048, hd=128)
//            -> out proj -> residual.   B=8, C=512, L=2048, G=4, NH=4.
// Storage dtype: float32. Internal compute: bf16 MFMA, f32 accumulation.
// R3: attention restructured around S^T (MFMA operands swapped) ->
//     per-lane softmax state (2 shfls, was 4), ds_write_b64 P staging
//     (was 64x ds_write_b16), 64-row Q tiles -> 1024 blocks -> 50% occupancy.
// ---------------------------------------------------------------------------

typedef unsigned short u16;
typedef unsigned long long u64;
typedef __attribute__((ext_vector_type(8)))  short          bf16x8;  // MFMA A/B frag
typedef __attribute__((ext_vector_type(4)))  float          f32x4;   // MFMA C/D frag
typedef __attribute__((ext_vector_type(4)))  unsigned int   u32x4;   // 16B copy
typedef __attribute__((ext_vector_type(8)))  unsigned short u16x8;

#define MFMA16(a, b, c) __builtin_amdgcn_mfma_f32_16x16x32_bf16((a), (b), (c), 0, 0, 0)

__device__ __forceinline__ u16 f2bf(float f) {
    union { float f; unsigned int i; } cv;
    cv.f = f;
    unsigned int u = cv.i;
    u += 0x7fffu + ((u >> 16) & 1);   // RNE
    return (u16)(u >> 16);
}

#define BATCH 8
#define CCH   512
#define LEN   2048
#define NGRP  4
#define NHEAD 4
#define HD    128
#define GSIZE (128 * 2048)   // elements per (b, group)

// ---------------------------------------------------------------------------
// 0) Convert the four 512x512 f32 weight matrices to bf16 (once per launch).
// ---------------------------------------------------------------------------
__global__ __launch_bounds__(256) void wcvt_k(const float* __restrict__ w0,
                                              const float* __restrict__ w1,
                                              const float* __restrict__ w2,
                                              const float* __restrict__ w3,
                                              u16* __restrict__ dst) {
    const int mat = blockIdx.y;
    const float* src = (mat == 0) ? w0 : (mat == 1) ? w1 : (mat == 2) ? w2 : w3;
    const size_t base = (size_t)blockIdx.x * 2048 + (size_t)threadIdx.x * 8;
    f32x4 a = *(const f32x4*)(src + base);
    f32x4 b = *(const f32x4*)(src + base + 4);
    u16x8 o;
    for (int u = 0; u < 4; ++u) { o[u] = f2bf(a[u]); o[u + 4] = f2bf(b[u]); }
    *(u16x8*)(dst + (size_t)mat * 262144 + base) = o;
}

// ---------------------------------------------------------------------------
// 1) GroupNorm partial stats (f32 input): 256 blocks, 16 channels of one (b,g).
// ---------------------------------------------------------------------------
__global__ __launch_bounds__(256) void gn_stats_k(const float* __restrict__ x,
                                                  float* __restrict__ stats) {
    const int bid   = blockIdx.x;       // 0..255
    const int grp   = bid >> 3;         // b*4+g
    const int chunk = bid & 7;          // 16-channel slab
    const int b = grp >> 2, g = grp & 3;
    const float* base = x + ((size_t)(b * CCH + g * 128 + chunk * 16)) * LEN;

    float s = 0.f, ss = 0.f;
    for (int i = 0; i < 32; ++i) {
        int cid = threadIdx.x + i * 256;          // 0..8191 chunks of 4
        f32x4 dv = *(const f32x4*)(base + (size_t)cid * 4);
        for (int u = 0; u < 4; ++u) { s += dv[u]; ss += dv[u] * dv[u]; }
    }
    for (int m = 1; m < 64; m <<= 1) {
        s  += __shfl_xor(s,  m, 64);
        ss += __shfl_xor(ss, m, 64);
    }
    __shared__ float red[8];
    int wid = threadIdx.x >> 6, lane = threadIdx.x & 63;
    if (lane == 0) { red[wid * 2] = s; red[wid * 2 + 1] = ss; }
    __syncthreads();
    if (threadIdx.x == 0) {
        float ts  = red[0] + red[2] + red[4] + red[6];
        float tss = red[1] + red[3] + red[5] + red[7];
        atomicAdd(&stats[grp * 2],     ts);
        atomicAdd(&stats[grp * 2 + 1], tss);
    }
}

// ---------------------------------------------------------------------------
// 2) GroupNorm apply + transpose: x[b,c,l] (f32) -> hT[b,l,c] (bf16).
//    64x64 tiles through LDS.
// ---------------------------------------------------------------------------
__global__ __launch_bounds__(256) void gn_apply_k(const float* __restrict__ x,
                                                  const float* __restrict__ gns,
                                                  const float* __restrict__ gnb,
                                                  const float* __restrict__ stats,
                                                  u16* __restrict__ hT) {
    __shared__ u16 Ts[64 * 72];
    const int b = blockIdx.z, c0 = blockIdx.y * 64, l0 = blockIdx.x * 64;
    const int g = c0 >> 7;
    const int tid = threadIdx.x;

    float sum   = stats[(b * NGRP + g) * 2];
    float sumsq = stats[(b * NGRP + g) * 2 + 1];
    const float invN = 1.f / (float)GSIZE;
    float mean = sum * invN;
    float var  = sumsq * invN - mean * mean;
    float rstd = rsqrtf(var + 1e-6f);

    for (int i = 0; i < 4; ++i) {
        int cid = tid + i * 256;          // 0..1023
        int row = cid >> 4, c4 = cid & 15; // row = channel in tile, col = c4*4
        int c = c0 + row;
        float sc = gns[c] * rstd;
        float bi = gnb[c] - mean * sc;
        f32x4 dv = *(const f32x4*)(x + ((size_t)(b * CCH + c)) * LEN + l0 + c4 * 4);
        for (int u = 0; u < 4; ++u)
            Ts[row * 72 + c4 * 4 + u] = f2bf(dv[u] * sc + bi);
    }
    __syncthreads();
    for (int i = 0; i < 2; ++i) {
        int cid = tid + i * 256;          // 0..511
        int lrow = cid >> 3, c8 = cid & 7;
        u16x8 ov;
        for (int u = 0; u < 8; ++u) ov[u] = Ts[(c8 * 8 + u) * 72 + lrow];
        *(u16x8*)(hT + ((size_t)b * LEN + l0 + lrow) * CCH + c0 + c8 * 8) = ov;
    }
}

// ---------------------------------------------------------------------------
// GEMM: D[m][n] = sum_k A[m][k]*B[n][k]; operands row-major [row, 512] bf16.
// MODE 0: A=hT[b] (m=l), B=wq_bf/wk_bf (n=o, N=1024) -> qT/kT (bf16) + bias
// MODE 1: A=wv_bf (m=o), B=hT[b] (n=l) -> v[b,c,l] (bf16) + bias
// MODE 2: A=wo_bf (m=o), B=attnT[b] (n=l) -> out[b,c,l] (f32) + bias + x
// 128x128x(K=512) tiles, BK=64, 4 waves (2x2), 64 f32 acc/lane.
// ---------------------------------------------------------------------------
template <int MODE>
__global__ __launch_bounds__(256, 2) void gemm_k(const u16* __restrict__ A0,
                                                 const u16* __restrict__ B0,
                                                 const u16* __restrict__ B1,
                                                 const float* __restrict__ bias0,
                                                 const float* __restrict__ bias1,
                                                 const float* __restrict__ resid,
                                                 void* __restrict__ out0v,
                                                 u16* __restrict__ out1) {
    __shared__ u16 As[128 * 72];
    __shared__ u16 Bs[128 * 72];
    const int b  = blockIdx.z;
    const int n0 = blockIdx.x * 128;
    const int m0 = blockIdx.y * 128;
    const int tid = threadIdx.x;
    const int lane = tid & 63, wid = tid >> 6;
    const int quad = lane >> 4, l15 = lane & 15;
    const int wm = (wid & 1) * 64, wn = (wid >> 1) * 64;

    const u16* Arow;
    if constexpr (MODE == 0) Arow = A0 + ((size_t)b * LEN + m0) * 512;
    else                     Arow = A0 + (size_t)m0 * 512;

    const u16* Brow;
    int col0 = 0;
    if constexpr (MODE == 0) {
        if (n0 < 512) { Brow = B0 + (size_t)n0 * 512;         col0 = n0; }
        else          { Brow = B1 + (size_t)(n0 - 512) * 512;  col0 = n0 - 512; }
    } else {
        Brow = B0 + ((size_t)b * LEN + n0) * 512;
    }

    f32x4 acc[4][4] = {};

    for (int kk = 0; kk < 8; ++kk) {
        const int k0 = kk * 64;
        __syncthreads();
        for (int i = 0; i < 4; ++i) {
            int cid = tid + i * 256;          // 0..1023
            int row = cid >> 3, c8 = cid & 7;
            *(u32x4*)(&As[row * 72 + c8 * 8]) =
                *(const u32x4*)(Arow + (size_t)row * 512 + k0 + c8 * 8);
            *(u32x4*)(&Bs[row * 72 + c8 * 8]) =
                *(const u32x4*)(Brow + (size_t)row * 512 + k0 + c8 * 8);
        }
        __syncthreads();
        for (int ks = 0; ks < 2; ++ks) {
            bf16x8 af[4], bfr[4];
            for (int t = 0; t < 4; ++t) {
                af[t]  = *(const bf16x8*)(&As[(wm + t * 16 + l15) * 72 + ks * 32 + quad * 8]);
                bfr[t] = *(const bf16x8*)(&Bs[(wn + t * 16 + l15) * 72 + ks * 32 + quad * 8]);
            }
            for (int mt = 0; mt < 4; ++mt)
                for (int nt = 0; nt < 4; ++nt)
                    acc[mt][nt] = MFMA16(af[mt], bfr[nt], acc[mt][nt]);
        }
    }

    if constexpr (MODE == 0) {
        const float* biasp = (n0 < 512) ? (bias0 + col0) : (bias1 + col0);
        u16* outp = (n0 < 512) ? (u16*)out0v : out1;
        for (int nt = 0; nt < 4; ++nt) {
            int nl = wn + nt * 16 + l15;
            float bv_ = biasp[nl];
            for (int mt = 0; mt < 4; ++mt)
                for (int r = 0; r < 4; ++r) {
                    int ml = wm + mt * 16 + quad * 4 + r;
                    size_t idx = ((size_t)b * LEN + m0 + ml) * 512 + col0 + nl;
                    outp[idx] = f2bf(acc[mt][nt][r] + bv_);
                }
        }
    } else {
        for (int mt = 0; mt < 4; ++mt)
            for (int r = 0; r < 4; ++r) {
                int ml = wm + mt * 16 + quad * 4 + r;
                float bv_ = bias0[m0 + ml];
                for (int nt = 0; nt < 4; ++nt) {
                    int nl = wn + nt * 16 + l15;
                    size_t idx = ((size_t)(b * 512 + m0 + ml)) * LEN + n0 + nl;
                    float val = acc[mt][nt][r] + bv_;
                    if constexpr (MODE == 2) {
                        ((float*)out0v)[idx] = val + resid[idx];
                    } else {
                        ((u16*)out0v)[idx] = f2bf(val);
                    }
                }
            }
    }
}

// ---------------------------------------------------------------------------
// Flash attention v2 (S^T form). Block = (b, h, 64-query tile), 4 waves,
// each wave owns 16 query rows (m = wid*16 + l15 per lane).
// S^T = MFMA(A=K, B=Q): D rows = j (keys), cols = m. Per-query softmax state
// is per-lane (replicated across quads); reductions = in-lane + 2 shfl_xor.
// P[m][j] row-major in LDS via ds_write_b64 (4 consecutive j per lane);
// PV A-frags read back as ds_read_b128. P overlays Ks rows 0..63.
// V B-frags straight from global (L2-resident). Output -> attnT[b, l, c].
// ---------------------------------------------------------------------------
__global__ __launch_bounds__(256, 4) void attn_k(const u16* __restrict__ qT,
                                                 const u16* __restrict__ kT,
                                                 const u16* __restrict__ v,
                                                 u16* __restrict__ attnT) {
    __shared__ u16 Ks[128 * 136];   // 34.8 KB; rows 0..63 double as P buffer
    const int b = blockIdx.z, h = blockIdx.y;
    const int i0 = blockIdx.x * 64;
    const int tid = threadIdx.x, lane = tid & 63, wid = tid >> 6;
    const int quad = lane >> 4, l15 = lane & 15;
    const int mrow = i0 + wid * 16 + l15;     // this lane's query row

    // Q B-frags, register resident: B[m=l15][k=d]
    bf16x8 qa[4];
    for (int ks = 0; ks < 4; ++ks)
        qa[ks] = *(const bf16x8*)(qT + ((size_t)b * LEN + mrow) * 512 + h * HD +
                                  ks * 32 + quad * 8);

    float mst = -3.0e38f, lst = 0.f;          // per-lane (m = l15), quad-replicated
    f32x4 oacc[8] = {};

    const float SL2E = 0.08838834764831845f * 1.4426950408889634f; // scale*log2(e)

    for (int jt = 0; jt < 16; ++jt) {
        const int j0 = jt * 128;
        __syncthreads();   // prev iter's P reads done before K restage
        for (int i = 0; i < 8; ++i) {
            int cid = tid + i * 256;           // 0..2047
            int row = cid >> 4, c8 = cid & 15;
            *(u32x4*)(&Ks[row * 136 + c8 * 8]) =
                *(const u32x4*)(kT + ((size_t)b * LEN + j0 + row) * 512 + h * HD + c8 * 8);
        }
        __syncthreads();

        // S^T: st[nt] rows = j = nt*16 + quad*4 + r, cols = m = l15
        f32x4 st[8] = {};
        for (int nt = 0; nt < 8; ++nt)
            for (int ks = 0; ks < 4; ++ks) {
                bf16x8 kf = *(const bf16x8*)(&Ks[(nt * 16 + l15) * 136 + ks * 32 + quad * 8]);
                st[nt] = MFMA16(kf, qa[ks], st[nt]);
            }

        // online softmax in log2 domain; state per lane (m = l15)
        float rm = -3.0e38f;
        for (int nt = 0; nt < 8; ++nt)
            for (int r = 0; r < 4; ++r) rm = fmaxf(rm, st[nt][r]);
        rm *= SL2E;
        rm = fmaxf(rm, __shfl_xor(rm, 16, 64));
        rm = fmaxf(rm, __shfl_xor(rm, 32, 64));
        float mnew  = fmaxf(mst, rm);
        float alpha = __builtin_amdgcn_exp2f(mst - mnew);
        mst = mnew;
        float rs = 0.f;
        for (int nt = 0; nt < 8; ++nt)
            for (int r = 0; r < 4; ++r) {
                float p = __builtin_amdgcn_exp2f(st[nt][r] * SL2E - mnew);
                st[nt][r] = p;
                rs += p;
            }
        rs += __shfl_xor(rs, 16, 64);
        rs += __shfl_xor(rs, 32, 64);
        lst = lst * alpha + rs;

        // rescale O accumulator: rows of oacc are m = quad*4 + r
        float av[4];
        for (int r = 0; r < 4; ++r) av[r] = __shfl(alpha, quad * 4 + r, 16);
        for (int dt = 0; dt < 8; ++dt)
            for (int r = 0; r < 4; ++r) oacc[dt][r] *= av[r];

        // all waves' QK^T reads of Ks done before P overwrites rows 0..63
        __syncthreads();

        // P[m][j] row-major, m = wid*16 + l15: 4 consecutive j per (nt) -> b64
        for (int nt = 0; nt < 8; ++nt) {
            u64 packed =  (u64)f2bf(st[nt][0])
                       | ((u64)f2bf(st[nt][1]) << 16)
                       | ((u64)f2bf(st[nt][2]) << 32)
                       | ((u64)f2bf(st[nt][3]) << 48);
            *(u64*)(&Ks[(wid * 16 + l15) * 136 + nt * 16 + quad * 4]) = packed;
        }

        // PV: O[m][d] += P[m][j] * v[d][j]; own wave's rows only -> no barrier
        for (int ks = 0; ks < 4; ++ks) {
            bf16x8 pf = *(const bf16x8*)(&Ks[(wid * 16 + l15) * 136 + ks * 32 + quad * 8]);
            for (int dt = 0; dt < 8; ++dt) {
                bf16x8 vf = *(const bf16x8*)(v + ((size_t)(b * CCH + h * HD + dt * 16 + l15)) * LEN +
                                             j0 + ks * 32 + quad * 8);
                oacc[dt] = MFMA16(pf, vf, oacc[dt]);
            }
        }
    }

    float inv = 1.f / lst;
    float iv[4];
    for (int r = 0; r < 4; ++r) iv[r] = __shfl(inv, quad * 4 + r, 16);
    for (int r = 0; r < 4; ++r) {
        int m = i0 + wid * 16 + quad * 4 + r;
        for (int dt = 0; dt < 8; ++dt) {
            int d = dt * 16 + l15;
            attnT[((size_t)b * LEN + m) * 512 + h * HD + d] = f2bf(oacc[dt][r] * iv[r]);
        }
    }
}

// ---------------------------------------------------------------------------
extern "C" void kernel_launch(void* const* d_in, const int* in_sizes, int n_in,
                              void* d_out, int out_size, void* d_ws, size_t ws_size,
                              hipStream_t stream) {
    const float* x   = (const float*)d_in[0];
    const float* gns = (const float*)d_in[1];
    const float* gnb = (const float*)d_in[2];
    const float* wq  = (const float*)d_in[3];
    const float* bq  = (const float*)d_in[4];
    const float* wk  = (const float*)d_in[5];
    const float* bk  = (const float*)d_in[6];
    const float* wv  = (const float*)d_in[7];
    const float* bv  = (const float*)d_in[8];
    const float* wo  = (const float*)d_in[9];
    const float* bo  = (const float*)d_in[10];
    float* out = (float*)d_out;

    const size_t NEL = (size_t)BATCH * CCH * LEN;   // 8388608
    float* stats = (float*)d_ws;                     // 64 floats @ 0
    u16* wcat  = (u16*)((char*)d_ws + 256);          // 4 x 512x512 bf16 weights
    u16* hT    = wcat + 4 * 262144;                  // bf16 [B,L,C]; reused as attnT
    u16* qT    = hT + NEL;
    u16* kT    = qT + NEL;
    u16* vbuf  = kT + NEL;
    u16* attnT = hT;   // hT dead after gemm<1>; alias to save 16 MB

    const u16* wq_bf = wcat;
    const u16* wk_bf = wcat + 262144;
    const u16* wv_bf = wcat + 2 * 262144;
    const u16* wo_bf = wcat + 3 * 262144;

    hipMemsetAsync(d_ws, 0, 256, stream);
    wcvt_k<<<dim3(128, 4), 256, 0, stream>>>(wq, wk, wv, wo, wcat);
    gn_stats_k<<<256, 256, 0, stream>>>(x, stats);
    gn_apply_k<<<dim3(32, 8, 8), 256, 0, stream>>>(x, gns, gnb, stats, hT);
    gemm_k<0><<<dim3(8, 16, 8), 256, 0, stream>>>(hT, wq_bf, wk_bf, bq, bk, nullptr, qT, kT);
    gemm_k<1><<<dim3(16, 4, 8), 256, 0, stream>>>(wv_bf, hT, nullptr, bv, nullptr, nullptr, vbuf, nullptr);
    attn_k<<<dim3(32, 4, 8), 256, 0, stream>>>(qT, kT, vbuf, attnT);
    gemm_k<2><<<dim3(16, 4, 8), 256, 0, stream>>>(wo_bf, attnT, nullptr, bo, nullptr, x, out, nullptr);
}

// Round 4
// 383.516 us; speedup vs baseline: 1.3091x; 1.3091x over previous
//
#include <hip/hip_runtime.h>

// ---------------------------------------------------------------------------
// AttnBlock: GroupNorm -> QKV (1x1 conv) -> 4-head attention (L=2048, hd=128)
//            -> out proj -> residual.   B=8, C=512, L=2048, G=4, NH=4.
// Storage dtype: float32. Internal compute: bf16 MFMA, f32 accumulation.
// R4: attention = 128-row Q tiles (2x frag reuse), V staged in LDS (bulk
//     cooperative loads, one drain), register double-buffer prefetch of next
//     K/V tile, XOR-swizzled unpadded LDS (64KB exactly), S^T softmax kept.
//     GEMM staging batched (loads in flight before LDS writes).
// ---------------------------------------------------------------------------

typedef unsigned short u16;
typedef unsigned long long u64;
typedef __attribute__((ext_vector_type(8)))  short          bf16x8;  // MFMA A/B frag
typedef __attribute__((ext_vector_type(4)))  float          f32x4;   // MFMA C/D frag
typedef __attribute__((ext_vector_type(4)))  unsigned int   u32x4;   // 16B copy
typedef __attribute__((ext_vector_type(8)))  unsigned short u16x8;

#define MFMA16(a, b, c) __builtin_amdgcn_mfma_f32_16x16x32_bf16((a), (b), (c), 0, 0, 0)

__device__ __forceinline__ u16 f2bf(float f) {
    union { float f; unsigned int i; } cv;
    cv.f = f;
    unsigned int u = cv.i;
    u += 0x7fffu + ((u >> 16) & 1);   // RNE
    return (u16)(u >> 16);
}

#define BATCH 8
#define CCH   512
#define LEN   2048
#define NGRP  4
#define NHEAD 4
#define HD    128
#define GSIZE (128 * 2048)   // elements per (b, group)

// ---------------------------------------------------------------------------
// 0) Convert the four 512x512 f32 weight matrices to bf16 (once per launch).
// ---------------------------------------------------------------------------
__global__ __launch_bounds__(256) void wcvt_k(const float* __restrict__ w0,
                                              const float* __restrict__ w1,
                                              const float* __restrict__ w2,
                                              const float* __restrict__ w3,
                                              u16* __restrict__ dst) {
    const int mat = blockIdx.y;
    const float* src = (mat == 0) ? w0 : (mat == 1) ? w1 : (mat == 2) ? w2 : w3;
    const size_t base = (size_t)blockIdx.x * 2048 + (size_t)threadIdx.x * 8;
    f32x4 a = *(const f32x4*)(src + base);
    f32x4 b = *(const f32x4*)(src + base + 4);
    u16x8 o;
    for (int u = 0; u < 4; ++u) { o[u] = f2bf(a[u]); o[u + 4] = f2bf(b[u]); }
    *(u16x8*)(dst + (size_t)mat * 262144 + base) = o;
}

// ---------------------------------------------------------------------------
// 1) GroupNorm partial stats (f32 input): 256 blocks, 16 channels of one (b,g).
// ---------------------------------------------------------------------------
__global__ __launch_bounds__(256) void gn_stats_k(const float* __restrict__ x,
                                                  float* __restrict__ stats) {
    const int bid   = blockIdx.x;       // 0..255
    const int grp   = bid >> 3;         // b*4+g
    const int chunk = bid & 7;          // 16-channel slab
    const int b = grp >> 2, g = grp & 3;
    const float* base = x + ((size_t)(b * CCH + g * 128 + chunk * 16)) * LEN;

    float s = 0.f, ss = 0.f;
    for (int i = 0; i < 32; ++i) {
        int cid = threadIdx.x + i * 256;          // 0..8191 chunks of 4
        f32x4 dv = *(const f32x4*)(base + (size_t)cid * 4);
        for (int u = 0; u < 4; ++u) { s += dv[u]; ss += dv[u] * dv[u]; }
    }
    for (int m = 1; m < 64; m <<= 1) {
        s  += __shfl_xor(s,  m, 64);
        ss += __shfl_xor(ss, m, 64);
    }
    __shared__ float red[8];
    int wid = threadIdx.x >> 6, lane = threadIdx.x & 63;
    if (lane == 0) { red[wid * 2] = s; red[wid * 2 + 1] = ss; }
    __syncthreads();
    if (threadIdx.x == 0) {
        float ts  = red[0] + red[2] + red[4] + red[6];
        float tss = red[1] + red[3] + red[5] + red[7];
        atomicAdd(&stats[grp * 2],     ts);
        atomicAdd(&stats[grp * 2 + 1], tss);
    }
}

// ---------------------------------------------------------------------------
// 2) GroupNorm apply + transpose: x[b,c,l] (f32) -> hT[b,l,c] (bf16).
//    64x64 tiles through LDS.
// ---------------------------------------------------------------------------
__global__ __launch_bounds__(256) void gn_apply_k(const float* __restrict__ x,
                                                  const float* __restrict__ gns,
                                                  const float* __restrict__ gnb,
                                                  const float* __restrict__ stats,
                                                  u16* __restrict__ hT) {
    __shared__ u16 Ts[64 * 72];
    const int b = blockIdx.z, c0 = blockIdx.y * 64, l0 = blockIdx.x * 64;
    const int g = c0 >> 7;
    const int tid = threadIdx.x;

    float sum   = stats[(b * NGRP + g) * 2];
    float sumsq = stats[(b * NGRP + g) * 2 + 1];
    const float invN = 1.f / (float)GSIZE;
    float mean = sum * invN;
    float var  = sumsq * invN - mean * mean;
    float rstd = rsqrtf(var + 1e-6f);

    for (int i = 0; i < 4; ++i) {
        int cid = tid + i * 256;          // 0..1023
        int row = cid >> 4, c4 = cid & 15; // row = channel in tile, col = c4*4
        int c = c0 + row;
        float sc = gns[c] * rstd;
        float bi = gnb[c] - mean * sc;
        f32x4 dv = *(const f32x4*)(x + ((size_t)(b * CCH + c)) * LEN + l0 + c4 * 4);
        for (int u = 0; u < 4; ++u)
            Ts[row * 72 + c4 * 4 + u] = f2bf(dv[u] * sc + bi);
    }
    __syncthreads();
    for (int i = 0; i < 2; ++i) {
        int cid = tid + i * 256;          // 0..511
        int lrow = cid >> 3, c8 = cid & 7;
        u16x8 ov;
        for (int u = 0; u < 8; ++u) ov[u] = Ts[(c8 * 8 + u) * 72 + lrow];
        *(u16x8*)(hT + ((size_t)b * LEN + l0 + lrow) * CCH + c0 + c8 * 8) = ov;
    }
}

// ---------------------------------------------------------------------------
// GEMM: D[m][n] = sum_k A[m][k]*B[n][k]; operands row-major [row, 512] bf16.
// MODE 0: A=hT[b] (m=l), B=wq_bf/wk_bf (n=o, N=1024) -> qT/kT (bf16) + bias
// MODE 1: A=wv_bf (m=o), B=hT[b] (n=l) -> v[b,c,l] (bf16) + bias
// MODE 2: A=wo_bf (m=o), B=attnT[b] (n=l) -> out[b,c,l] (f32) + bias + x
// 128x128x(K=512) tiles, BK=64, 4 waves (2x2), 64 f32 acc/lane.
// Staging: batched (all 8 global loads in flight, then LDS writes).
// ---------------------------------------------------------------------------
template <int MODE>
__global__ __launch_bounds__(256, 2) void gemm_k(const u16* __restrict__ A0,
                                                 const u16* __restrict__ B0,
                                                 const u16* __restrict__ B1,
                                                 const float* __restrict__ bias0,
                                                 const float* __restrict__ bias1,
                                                 const float* __restrict__ resid,
                                                 void* __restrict__ out0v,
                                                 u16* __restrict__ out1) {
    __shared__ u16 As[128 * 72];
    __shared__ u16 Bs[128 * 72];
    const int b  = blockIdx.z;
    const int n0 = blockIdx.x * 128;
    const int m0 = blockIdx.y * 128;
    const int tid = threadIdx.x;
    const int lane = tid & 63, wid = tid >> 6;
    const int quad = lane >> 4, l15 = lane & 15;
    const int wm = (wid & 1) * 64, wn = (wid >> 1) * 64;

    const u16* Arow;
    if constexpr (MODE == 0) Arow = A0 + ((size_t)b * LEN + m0) * 512;
    else                     Arow = A0 + (size_t)m0 * 512;

    const u16* Brow;
    int col0 = 0;
    if constexpr (MODE == 0) {
        if (n0 < 512) { Brow = B0 + (size_t)n0 * 512;         col0 = n0; }
        else          { Brow = B1 + (size_t)(n0 - 512) * 512;  col0 = n0 - 512; }
    } else {
        Brow = B0 + ((size_t)b * LEN + n0) * 512;
    }

    f32x4 acc[4][4] = {};
    const int srow = tid >> 3, sc8 = tid & 7;   // staging: 8 chunks/row, rows +32/i

    for (int kk = 0; kk < 8; ++kk) {
        const int k0 = kk * 64;
        u32x4 abuf[4], bbuf[4];
#pragma unroll
        for (int i = 0; i < 4; ++i) {
            int row = srow + i * 32;
            abuf[i] = *(const u32x4*)(Arow + (size_t)row * 512 + k0 + sc8 * 8);
            bbuf[i] = *(const u32x4*)(Brow + (size_t)row * 512 + k0 + sc8 * 8);
        }
        __syncthreads();
#pragma unroll
        for (int i = 0; i < 4; ++i) {
            int row = srow + i * 32;
            *(u32x4*)(&As[row * 72 + sc8 * 8]) = abuf[i];
            *(u32x4*)(&Bs[row * 72 + sc8 * 8]) = bbuf[i];
        }
        __syncthreads();
        for (int ks = 0; ks < 2; ++ks) {
            bf16x8 af[4], bfr[4];
            for (int t = 0; t < 4; ++t) {
                af[t]  = *(const bf16x8*)(&As[(wm + t * 16 + l15) * 72 + ks * 32 + quad * 8]);
                bfr[t] = *(const bf16x8*)(&Bs[(wn + t * 16 + l15) * 72 + ks * 32 + quad * 8]);
            }
            for (int mt = 0; mt < 4; ++mt)
                for (int nt = 0; nt < 4; ++nt)
                    acc[mt][nt] = MFMA16(af[mt], bfr[nt], acc[mt][nt]);
        }
    }

    if constexpr (MODE == 0) {
        const float* biasp = (n0 < 512) ? (bias0 + col0) : (bias1 + col0);
        u16* outp = (n0 < 512) ? (u16*)out0v : out1;
        for (int nt = 0; nt < 4; ++nt) {
            int nl = wn + nt * 16 + l15;
            float bv_ = biasp[nl];
            for (int mt = 0; mt < 4; ++mt)
                for (int r = 0; r < 4; ++r) {
                    int ml = wm + mt * 16 + quad * 4 + r;
                    size_t idx = ((size_t)b * LEN + m0 + ml) * 512 + col0 + nl;
                    outp[idx] = f2bf(acc[mt][nt][r] + bv_);
                }
        }
    } else {
        for (int mt = 0; mt < 4; ++mt)
            for (int r = 0; r < 4; ++r) {
                int ml = wm + mt * 16 + quad * 4 + r;
                float bv_ = bias0[m0 + ml];
                for (int nt = 0; nt < 4; ++nt) {
                    int nl = wn + nt * 16 + l15;
                    size_t idx = ((size_t)(b * 512 + m0 + ml)) * LEN + n0 + nl;
                    float val = acc[mt][nt][r] + bv_;
                    if constexpr (MODE == 2) {
                        ((float*)out0v)[idx] = val + resid[idx];
                    } else {
                        ((u16*)out0v)[idx] = f2bf(val);
                    }
                }
            }
    }
}

// ---------------------------------------------------------------------------
// Flash attention v3 (S^T form, K+V in LDS, register prefetch).
// Block = (b, h, 128-query tile), 4 waves; wave owns 32 q-rows (2 m-frags).
// LDS: Ks[128x128] + Vs[128x128] = 64 KB exactly, XOR-swizzled 16B chunks
//   (physical chunk = logical ^ (row & 7)) -> conflict-free, no padding.
// Per j-tile: write prefetched K,V regs -> LDS; prefetch next K during
// QK+softmax; S^T = MFMA(A=K, B=Q) (kf reused 2x); per-lane softmax state;
// P (bf16) overlays Ks; prefetch next V during PV; PV reads Vs (vf reused 2x).
// ---------------------------------------------------------------------------
__global__ __launch_bounds__(256, 2) void attn_k(const u16* __restrict__ qT,
                                                 const u16* __restrict__ kT,
                                                 const u16* __restrict__ v,
                                                 u16* __restrict__ attnT) {
    __shared__ u16 Ks[128 * 128];   // K tile / P tile (overlay)
    __shared__ u16 Vs[128 * 128];
    const int b = blockIdx.z, h = blockIdx.y;
    const int i0 = blockIdx.x * 128;
    const int tid = threadIdx.x, lane = tid & 63, wid = tid >> 6;
    const int quad = lane >> 4, l15 = lane & 15;

    // Q B-frags for this wave's 32 m-rows (mf=0,1)
    bf16x8 qa[2][4];
    for (int mf = 0; mf < 2; ++mf)
        for (int ks = 0; ks < 4; ++ks) {
            int m = i0 + wid * 32 + mf * 16 + l15;
            qa[mf][ks] = *(const bf16x8*)(qT + ((size_t)b * LEN + m) * 512 + h * HD +
                                          ks * 32 + quad * 8);
        }

    float mst[2] = {-3.0e38f, -3.0e38f}, lst[2] = {0.f, 0.f};
    f32x4 oacc[2][8] = {};

    const float SL2E = 0.08838834764831845f * 1.4426950408889634f; // scale*log2e

    // staging geometry: thread covers rows (tid>>4)+16i, fixed chunk col tid&15
    const int srow0 = tid >> 4, sc = tid & 15;
    const u16* kbase = kT + ((size_t)b * LEN) * 512 + h * HD + sc * 8;
    const u16* vbase = v + ((size_t)(b * CCH + h * HD)) * LEN + sc * 8;

    u32x4 kreg[8], vreg[8];
#pragma unroll
    for (int i = 0; i < 8; ++i) {
        int row = srow0 + i * 16;
        kreg[i] = *(const u32x4*)(kbase + (size_t)row * 512);
        vreg[i] = *(const u32x4*)(vbase + (size_t)row * LEN);
    }

    for (int jt = 0; jt < 16; ++jt) {
        const int j0 = jt * 128;
        __syncthreads();   // prev iter's P/V reads done before restage
#pragma unroll
        for (int i = 0; i < 8; ++i) {
            int row = srow0 + i * 16;
            int pc = sc ^ (row & 7);
            *(u32x4*)(&Ks[row * 128 + pc * 8]) = kreg[i];
            *(u32x4*)(&Vs[row * 128 + pc * 8]) = vreg[i];
        }
        __syncthreads();

        // prefetch next K tile (latency hidden behind QK + softmax)
        if (jt < 15) {
#pragma unroll
            for (int i = 0; i < 8; ++i) {
                int row = srow0 + i * 16;
                kreg[i] = *(const u32x4*)(kbase + (size_t)(j0 + 128 + row) * 512);
            }
        }

        // S^T: st[mf][nt] rows j = nt*16+quad*4+r, cols m = wid*32+mf*16+l15
        f32x4 st[2][8] = {};
        for (int nt = 0; nt < 8; ++nt) {
            int r = nt * 16 + l15;
            for (int ks = 0; ks < 4; ++ks) {
                bf16x8 kf = *(const bf16x8*)(&Ks[r * 128 + ((ks * 4 + quad) ^ (r & 7)) * 8]);
                st[0][nt] = MFMA16(kf, qa[0][ks], st[0][nt]);
                st[1][nt] = MFMA16(kf, qa[1][ks], st[1][nt]);
            }
        }

        // online softmax per mf; state per lane (m = l15), quad-replicated
        for (int mf = 0; mf < 2; ++mf) {
            float rm = -3.0e38f;
            for (int nt = 0; nt < 8; ++nt)
                for (int r = 0; r < 4; ++r) rm = fmaxf(rm, st[mf][nt][r]);
            rm *= SL2E;
            rm = fmaxf(rm, __shfl_xor(rm, 16, 64));
            rm = fmaxf(rm, __shfl_xor(rm, 32, 64));
            float mnew  = fmaxf(mst[mf], rm);
            float alpha = __builtin_amdgcn_exp2f(mst[mf] - mnew);
            mst[mf] = mnew;
            float rs = 0.f;
            for (int nt = 0; nt < 8; ++nt)
                for (int r = 0; r < 4; ++r) {
                    float p = __builtin_amdgcn_exp2f(st[mf][nt][r] * SL2E - mnew);
                    st[mf][nt][r] = p;
                    rs += p;
                }
            rs += __shfl_xor(rs, 16, 64);
            rs += __shfl_xor(rs, 32, 64);
            lst[mf] = lst[mf] * alpha + rs;
            float av[4];
            for (int r = 0; r < 4; ++r) av[r] = __shfl(alpha, quad * 4 + r, 16);
            for (int dt = 0; dt < 8; ++dt)
                for (int r = 0; r < 4; ++r) oacc[mf][dt][r] *= av[r];
        }

        // all waves' QK reads of Ks done before P overwrites it
        __syncthreads();

        // P[m][j] (bf16) -> Ks region, swizzled; b64 = 4 consecutive j
        for (int mf = 0; mf < 2; ++mf) {
            int m = wid * 32 + mf * 16 + l15;
            for (int nt = 0; nt < 8; ++nt) {
                u64 packed =  (u64)f2bf(st[mf][nt][0])
                           | ((u64)f2bf(st[mf][nt][1]) << 16)
                           | ((u64)f2bf(st[mf][nt][2]) << 32)
                           | ((u64)f2bf(st[mf][nt][3]) << 48);
                int pc = (nt * 2 + (quad >> 1)) ^ (m & 7);
                *(u64*)(&Ks[m * 128 + pc * 8 + (quad & 1) * 4]) = packed;
            }
        }

        // prefetch next V tile (latency hidden behind PV; st regs now dead)
        if (jt < 15) {
#pragma unroll
            for (int i = 0; i < 8; ++i) {
                int row = srow0 + i * 16;
                vreg[i] = *(const u32x4*)(vbase + (size_t)row * LEN + j0 + 128);
            }
        }

        // PV: O[m][d] += P[m][j] * V[d][j]; own wave's P rows -> no barrier
        for (int ks = 0; ks < 4; ++ks) {
            bf16x8 pf[2];
            for (int mf = 0; mf < 2; ++mf) {
                int m = wid * 32 + mf * 16 + l15;
                pf[mf] = *(const bf16x8*)(&Ks[m * 128 + ((ks * 4 + quad) ^ (m & 7)) * 8]);
            }
            for (int dt = 0; dt < 8; ++dt) {
                int d = dt * 16 + l15;
                bf16x8 vf = *(const bf16x8*)(&Vs[d * 128 + ((ks * 4 + quad) ^ (d & 7)) * 8]);
                oacc[0][dt] = MFMA16(pf[0], vf, oacc[0][dt]);
                oacc[1][dt] = MFMA16(pf[1], vf, oacc[1][dt]);
            }
        }
    }

    for (int mf = 0; mf < 2; ++mf) {
        float inv = 1.f / lst[mf];
        float iv[4];
        for (int r = 0; r < 4; ++r) iv[r] = __shfl(inv, quad * 4 + r, 16);
        for (int r = 0; r < 4; ++r) {
            int m = i0 + wid * 32 + mf * 16 + quad * 4 + r;
            for (int dt = 0; dt < 8; ++dt) {
                int d = dt * 16 + l15;
                attnT[((size_t)b * LEN + m) * 512 + h * HD + d] =
                    f2bf(oacc[mf][dt][r] * iv[r]);
            }
        }
    }
}

// ---------------------------------------------------------------------------
extern "C" void kernel_launch(void* const* d_in, const int* in_sizes, int n_in,
                              void* d_out, int out_size, void* d_ws, size_t ws_size,
                              hipStream_t stream) {
    const float* x   = (const float*)d_in[0];
    const float* gns = (const float*)d_in[1];
    const float* gnb = (const float*)d_in[2];
    const float* wq  = (const float*)d_in[3];
    const float* bq  = (const float*)d_in[4];
    const float* wk  = (const float*)d_in[5];
    const float* bk  = (const float*)d_in[6];
    const float* wv  = (const float*)d_in[7];
    const float* bv  = (const float*)d_in[8];
    const float* wo  = (const float*)d_in[9];
    const float* bo  = (const float*)d_in[10];
    float* out = (float*)d_out;

    const size_t NEL = (size_t)BATCH * CCH * LEN;   // 8388608
    float* stats = (float*)d_ws;                     // 64 floats @ 0
    u16* wcat  = (u16*)((char*)d_ws + 256);          // 4 x 512x512 bf16 weights
    u16* hT    = wcat + 4 * 262144;                  // bf16 [B,L,C]; reused as attnT
    u16* qT    = hT + NEL;
    u16* kT    = qT + NEL;
    u16* vbuf  = kT + NEL;
    u16* attnT = hT;   // hT dead after gemm<1>; alias to save 16 MB

    const u16* wq_bf = wcat;
    const u16* wk_bf = wcat + 262144;
    const u16* wv_bf = wcat + 2 * 262144;
    const u16* wo_bf = wcat + 3 * 262144;

    hipMemsetAsync(d_ws, 0, 256, stream);
    wcvt_k<<<dim3(128, 4), 256, 0, stream>>>(wq, wk, wv, wo, wcat);
    gn_stats_k<<<256, 256, 0, stream>>>(x, stats);
    gn_apply_k<<<dim3(32, 8, 8), 256, 0, stream>>>(x, gns, gnb, stats, hT);
    gemm_k<0><<<dim3(8, 16, 8), 256, 0, stream>>>(hT, wq_bf, wk_bf, bq, bk, nullptr, qT, kT);
    gemm_k<1><<<dim3(16, 4, 8), 256, 0, stream>>>(wv_bf, hT, nullptr, bv, nullptr, nullptr, vbuf, nullptr);
    attn_k<<<dim3(16, 4, 8), 256, 0, stream>>>(qT, kT, vbuf, attnT);
    gemm_k<2><<<dim3(16, 4, 8), 256, 0, stream>>>(wo_bf, attnT, nullptr, bo, nullptr, x, out, nullptr);
}

// Round 5
// 290.092 us; speedup vs baseline: 1.7307x; 1.3220x over previous
//
#include <hip/hip_runtime.h>

// ---------------------------------------------------------------------------
// AttnBlock: GroupNorm -> QKV (1x1 conv) -> 4-head attention (L=2048, hd=128)
//            -> out proj -> residual.   B=8, C=512, L=2048, G=4, NH=4.
// Storage dtype: float32. Internal compute: bf16 MFMA, f32 accumulation.
// R5: kill R4's scratch spills. K/V (attn) and A/B (gemm) staged via
//     __builtin_amdgcn_global_load_lds width=16 (no VGPR round-trip, no
//     ds_writes). XOR swizzle moved to the *global* address side so the
//     wave-uniform-base+lane*16 LDS landing pattern yields the swizzled
//     layout; all LDS reads stay 2-way-max on banks. No register prefetch.
// ---------------------------------------------------------------------------

typedef unsigned short u16;
typedef unsigned long long u64;
typedef __attribute__((ext_vector_type(8)))  short          bf16x8;  // MFMA A/B frag
typedef __attribute__((ext_vector_type(4)))  float          f32x4;   // MFMA C/D frag
typedef __attribute__((ext_vector_type(4)))  unsigned int   u32x4;   // 16B copy
typedef __attribute__((ext_vector_type(8)))  unsigned short u16x8;

#define MFMA16(a, b, c) __builtin_amdgcn_mfma_f32_16x16x32_bf16((a), (b), (c), 0, 0, 0)

__device__ __forceinline__ u16 f2bf(float f) {
    union { float f; unsigned int i; } cv;
    cv.f = f;
    unsigned int u = cv.i;
    u += 0x7fffu + ((u >> 16) & 1);   // RNE
    return (u16)(u >> 16);
}

// async 16B global->LDS (DMA; lands at lds_base + lane*16)
__device__ __forceinline__ void async16(const u16* g, u16* l) {
    __builtin_amdgcn_global_load_lds(
        (const __attribute__((address_space(1))) unsigned int*)g,
        (__attribute__((address_space(3))) unsigned int*)l, 16, 0, 0);
}

#define BATCH 8
#define CCH   512
#define LEN   2048
#define NGRP  4
#define NHEAD 4
#define HD    128
#define GSIZE (128 * 2048)   // elements per (b, group)

// ---------------------------------------------------------------------------
// 0) Convert the four 512x512 f32 weight matrices to bf16 (once per launch).
// ---------------------------------------------------------------------------
__global__ __launch_bounds__(256) void wcvt_k(const float* __restrict__ w0,
                                              const float* __restrict__ w1,
                                              const float* __restrict__ w2,
                                              const float* __restrict__ w3,
                                              u16* __restrict__ dst) {
    const int mat = blockIdx.y;
    const float* src = (mat == 0) ? w0 : (mat == 1) ? w1 : (mat == 2) ? w2 : w3;
    const size_t base = (size_t)blockIdx.x * 2048 + (size_t)threadIdx.x * 8;
    f32x4 a = *(const f32x4*)(src + base);
    f32x4 b = *(const f32x4*)(src + base + 4);
    u16x8 o;
    for (int u = 0; u < 4; ++u) { o[u] = f2bf(a[u]); o[u + 4] = f2bf(b[u]); }
    *(u16x8*)(dst + (size_t)mat * 262144 + base) = o;
}

// ---------------------------------------------------------------------------
// 1) GroupNorm partial stats (f32 input): 256 blocks, 16 channels of one (b,g).
// ---------------------------------------------------------------------------
__global__ __launch_bounds__(256) void gn_stats_k(const float* __restrict__ x,
                                                  float* __restrict__ stats) {
    const int bid   = blockIdx.x;       // 0..255
    const int grp   = bid >> 3;         // b*4+g
    const int chunk = bid & 7;          // 16-channel slab
    const int b = grp >> 2, g = grp & 3;
    const float* base = x + ((size_t)(b * CCH + g * 128 + chunk * 16)) * LEN;

    float s = 0.f, ss = 0.f;
    for (int i = 0; i < 32; ++i) {
        int cid = threadIdx.x + i * 256;          // 0..8191 chunks of 4
        f32x4 dv = *(const f32x4*)(base + (size_t)cid * 4);
        for (int u = 0; u < 4; ++u) { s += dv[u]; ss += dv[u] * dv[u]; }
    }
    for (int m = 1; m < 64; m <<= 1) {
        s  += __shfl_xor(s,  m, 64);
        ss += __shfl_xor(ss, m, 64);
    }
    __shared__ float red[8];
    int wid = threadIdx.x >> 6, lane = threadIdx.x & 63;
    if (lane == 0) { red[wid * 2] = s; red[wid * 2 + 1] = ss; }
    __syncthreads();
    if (threadIdx.x == 0) {
        float ts  = red[0] + red[2] + red[4] + red[6];
        float tss = red[1] + red[3] + red[5] + red[7];
        atomicAdd(&stats[grp * 2],     ts);
        atomicAdd(&stats[grp * 2 + 1], tss);
    }
}

// ---------------------------------------------------------------------------
// 2) GroupNorm apply + transpose: x[b,c,l] (f32) -> hT[b,l,c] (bf16).
//    64x64 tiles through LDS.
// ---------------------------------------------------------------------------
__global__ __launch_bounds__(256) void gn_apply_k(const float* __restrict__ x,
                                                  const float* __restrict__ gns,
                                                  const float* __restrict__ gnb,
                                                  const float* __restrict__ stats,
                                                  u16* __restrict__ hT) {
    __shared__ u16 Ts[64 * 72];
    const int b = blockIdx.z, c0 = blockIdx.y * 64, l0 = blockIdx.x * 64;
    const int g = c0 >> 7;
    const int tid = threadIdx.x;

    float sum   = stats[(b * NGRP + g) * 2];
    float sumsq = stats[(b * NGRP + g) * 2 + 1];
    const float invN = 1.f / (float)GSIZE;
    float mean = sum * invN;
    float var  = sumsq * invN - mean * mean;
    float rstd = rsqrtf(var + 1e-6f);

    for (int i = 0; i < 4; ++i) {
        int cid = tid + i * 256;          // 0..1023
        int row = cid >> 4, c4 = cid & 15; // row = channel in tile, col = c4*4
        int c = c0 + row;
        float sc = gns[c] * rstd;
        float bi = gnb[c] - mean * sc;
        f32x4 dv = *(const f32x4*)(x + ((size_t)(b * CCH + c)) * LEN + l0 + c4 * 4);
        for (int u = 0; u < 4; ++u)
            Ts[row * 72 + c4 * 4 + u] = f2bf(dv[u] * sc + bi);
    }
    __syncthreads();
    for (int i = 0; i < 2; ++i) {
        int cid = tid + i * 256;          // 0..511
        int lrow = cid >> 3, c8 = cid & 7;
        u16x8 ov;
        for (int u = 0; u < 8; ++u) ov[u] = Ts[(c8 * 8 + u) * 72 + lrow];
        *(u16x8*)(hT + ((size_t)b * LEN + l0 + lrow) * CCH + c0 + c8 * 8) = ov;
    }
}

// ---------------------------------------------------------------------------
// GEMM: D[m][n] = sum_k A[m][k]*B[n][k]; operands row-major [row, 512] bf16.
// MODE 0: A=hT[b] (m=l), B=wq_bf/wk_bf (n=o, N=1024) -> qT/kT (bf16) + bias
// MODE 1: A=wv_bf (m=o), B=hT[b] (n=l) -> v[b,c,l] (bf16) + bias
// MODE 2: A=wo_bf (m=o), B=attnT[b] (n=l) -> out[b,c,l] (f32) + bias + x
// 128x128x(K=512) tiles, BK=64, 4 waves (2x2), 64 f32 acc/lane.
// Staging: global_load_lds dwordx4, unpadded 128x64 tiles, XOR swizzle
//   (phys chunk pc holds logical chunk pc ^ (row&7); 8 chunks/row).
// ---------------------------------------------------------------------------
template <int MODE>
__global__ __launch_bounds__(256, 2) void gemm_k(const u16* __restrict__ A0,
                                                 const u16* __restrict__ B0,
                                                 const u16* __restrict__ B1,
                                                 const float* __restrict__ bias0,
                                                 const float* __restrict__ bias1,
                                                 const float* __restrict__ resid,
                                                 void* __restrict__ out0v,
                                                 u16* __restrict__ out1) {
    __shared__ u16 As[128 * 64];
    __shared__ u16 Bs[128 * 64];
    const int b  = blockIdx.z;
    const int n0 = blockIdx.x * 128;
    const int m0 = blockIdx.y * 128;
    const int tid = threadIdx.x;
    const int lane = tid & 63, wid = tid >> 6;
    const int quad = lane >> 4, l15 = lane & 15;
    const int wm = (wid & 1) * 64, wn = (wid >> 1) * 64;

    const u16* Arow;
    if constexpr (MODE == 0) Arow = A0 + ((size_t)b * LEN + m0) * 512;
    else                     Arow = A0 + (size_t)m0 * 512;

    const u16* Brow;
    int col0 = 0;
    if constexpr (MODE == 0) {
        if (n0 < 512) { Brow = B0 + (size_t)n0 * 512;         col0 = n0; }
        else          { Brow = B1 + (size_t)(n0 - 512) * 512;  col0 = n0 - 512; }
    } else {
        Brow = B0 + ((size_t)b * LEN + n0) * 512;
    }

    f32x4 acc[4][4] = {};
    // staging: instr i stages 8 rows (wid*32 + i*8 + lane>>3), chunk lane&7
    const int srl = lane >> 3, scl = lane & 7;

    for (int kk = 0; kk < 8; ++kk) {
        const int k0 = kk * 64;
        __syncthreads();
#pragma unroll
        for (int i = 0; i < 4; ++i) {
            int rloc = wid * 32 + i * 8 + srl;
            int lc = scl ^ (rloc & 7);
            async16(Arow + (size_t)rloc * 512 + k0 + lc * 8, &As[(wid * 32 + i * 8) * 64]);
            async16(Brow + (size_t)rloc * 512 + k0 + lc * 8, &Bs[(wid * 32 + i * 8) * 64]);
        }
        __syncthreads();
        for (int ks = 0; ks < 2; ++ks) {
            bf16x8 af[4], bfr[4];
            for (int t = 0; t < 4; ++t) {
                int ra = wm + t * 16 + l15, rb = wn + t * 16 + l15;
                af[t]  = *(const bf16x8*)(&As[ra * 64 + (((ks * 4 + quad) ^ (ra & 7))) * 8]);
                bfr[t] = *(const bf16x8*)(&Bs[rb * 64 + (((ks * 4 + quad) ^ (rb & 7))) * 8]);
            }
            for (int mt = 0; mt < 4; ++mt)
                for (int nt = 0; nt < 4; ++nt)
                    acc[mt][nt] = MFMA16(af[mt], bfr[nt], acc[mt][nt]);
        }
    }

    if constexpr (MODE == 0) {
        const float* biasp = (n0 < 512) ? (bias0 + col0) : (bias1 + col0);
        u16* outp = (n0 < 512) ? (u16*)out0v : out1;
        for (int nt = 0; nt < 4; ++nt) {
            int nl = wn + nt * 16 + l15;
            float bv_ = biasp[nl];
            for (int mt = 0; mt < 4; ++mt)
                for (int r = 0; r < 4; ++r) {
                    int ml = wm + mt * 16 + quad * 4 + r;
                    size_t idx = ((size_t)b * LEN + m0 + ml) * 512 + col0 + nl;
                    outp[idx] = f2bf(acc[mt][nt][r] + bv_);
                }
        }
    } else {
        for (int mt = 0; mt < 4; ++mt)
            for (int r = 0; r < 4; ++r) {
                int ml = wm + mt * 16 + quad * 4 + r;
                float bv_ = bias0[m0 + ml];
                for (int nt = 0; nt < 4; ++nt) {
                    int nl = wn + nt * 16 + l15;
                    size_t idx = ((size_t)(b * 512 + m0 + ml)) * LEN + n0 + nl;
                    float val = acc[mt][nt][r] + bv_;
                    if constexpr (MODE == 2) {
                        ((float*)out0v)[idx] = val + resid[idx];
                    } else {
                        ((u16*)out0v)[idx] = f2bf(val);
                    }
                }
            }
    }
}

// ---------------------------------------------------------------------------
// Flash attention v4 (S^T form, K+V staged via global_load_lds, no spills).
// Block = (b, h, 128-query tile), 4 waves; wave owns 32 q-rows (2 m-frags).
// LDS: Ks[128x128] + Vs[128x128] = 64 KB, XOR-swizzled 16B chunks
//   (phys chunk pc at row r holds logical chunk pc ^ (r&7); 16 chunks/row).
// Per j-tile: barrier -> issue 16 DMA loads (K+V, swizzle on global addr)
//   -> barrier (drain) -> QK^T (S^T via MFMA A=K,B=Q) -> per-lane online
//   softmax -> barrier -> P overlays Ks -> PV from Vs. Output attnT[b,l,c].
// ---------------------------------------------------------------------------
__global__ __launch_bounds__(256, 2) void attn_k(const u16* __restrict__ qT,
                                                 const u16* __restrict__ kT,
                                                 const u16* __restrict__ v,
                                                 u16* __restrict__ attnT) {
    __shared__ u16 Ks[128 * 128];   // K tile / P tile (overlay)
    __shared__ u16 Vs[128 * 128];
    const int b = blockIdx.z, h = blockIdx.y;
    const int i0 = blockIdx.x * 128;
    const int tid = threadIdx.x, lane = tid & 63, wid = tid >> 6;
    const int quad = lane >> 4, l15 = lane & 15;

    // Q B-frags for this wave's 32 m-rows (mf=0,1)
    bf16x8 qa[2][4];
    for (int mf = 0; mf < 2; ++mf)
        for (int ks = 0; ks < 4; ++ks) {
            int m = i0 + wid * 32 + mf * 16 + l15;
            qa[mf][ks] = *(const bf16x8*)(qT + ((size_t)b * LEN + m) * 512 + h * HD +
                                          ks * 32 + quad * 8);
        }

    float mst[2] = {-3.0e38f, -3.0e38f}, lst[2] = {0.f, 0.f};
    f32x4 oacc[2][8] = {};

    const float SL2E = 0.08838834764831845f * 1.4426950408889634f; // scale*log2e

    // staging geometry: DMA instr i stages 4 rows (wid*32 + i*4 + lane>>4),
    // lane's data lands at phys chunk lane&15 -> load logical chunk pc^(r&7)
    const int srw = lane >> 4, sc = lane & 15;
    const u16* kbase = kT + ((size_t)b * LEN) * 512 + h * HD;
    const u16* vbase = v + ((size_t)(b * CCH + h * HD)) * LEN;

    for (int jt = 0; jt < 16; ++jt) {
        const int j0 = jt * 128;
        __syncthreads();   // prev iter's P/V reads done before restage
#pragma unroll
        for (int i = 0; i < 8; ++i) {
            int rloc = wid * 32 + i * 4 + srw;       // row in tile (j for K, d for V)
            int lc = sc ^ (rloc & 7);
            async16(kbase + (size_t)(j0 + rloc) * 512 + lc * 8,
                    &Ks[(wid * 32 + i * 4) * 128]);
            async16(vbase + (size_t)rloc * LEN + j0 + lc * 8,
                    &Vs[(wid * 32 + i * 4) * 128]);
        }
        __syncthreads();   // DMA drained -> K,V tiles resident

        // S^T: st[mf][nt] rows j = nt*16+quad*4+r, cols m = wid*32+mf*16+l15
        f32x4 st[2][8] = {};
        for (int nt = 0; nt < 8; ++nt) {
            int r = nt * 16 + l15;
            for (int ks = 0; ks < 4; ++ks) {
                bf16x8 kf = *(const bf16x8*)(&Ks[r * 128 + ((ks * 4 + quad) ^ (r & 7)) * 8]);
                st[0][nt] = MFMA16(kf, qa[0][ks], st[0][nt]);
                st[1][nt] = MFMA16(kf, qa[1][ks], st[1][nt]);
            }
        }

        // online softmax per mf; state per lane (m = l15), quad-replicated
        for (int mf = 0; mf < 2; ++mf) {
            float rm = -3.0e38f;
            for (int nt = 0; nt < 8; ++nt)
                for (int r = 0; r < 4; ++r) rm = fmaxf(rm, st[mf][nt][r]);
            rm *= SL2E;
            rm = fmaxf(rm, __shfl_xor(rm, 16, 64));
            rm = fmaxf(rm, __shfl_xor(rm, 32, 64));
            float mnew  = fmaxf(mst[mf], rm);
            float alpha = __builtin_amdgcn_exp2f(mst[mf] - mnew);
            mst[mf] = mnew;
            float rs = 0.f;
            for (int nt = 0; nt < 8; ++nt)
                for (int r = 0; r < 4; ++r) {
                    float p = __builtin_amdgcn_exp2f(st[mf][nt][r] * SL2E - mnew);
                    st[mf][nt][r] = p;
                    rs += p;
                }
            rs += __shfl_xor(rs, 16, 64);
            rs += __shfl_xor(rs, 32, 64);
            lst[mf] = lst[mf] * alpha + rs;
            float av[4];
            for (int r = 0; r < 4; ++r) av[r] = __shfl(alpha, quad * 4 + r, 16);
            for (int dt = 0; dt < 8; ++dt)
                for (int r = 0; r < 4; ++r) oacc[mf][dt][r] *= av[r];
        }

        // all waves' QK reads of Ks done before P overwrites it
        __syncthreads();

        // P[m][j] (bf16) -> Ks region, swizzled; b64 = 4 consecutive j
        for (int mf = 0; mf < 2; ++mf) {
            int m = wid * 32 + mf * 16 + l15;
            for (int nt = 0; nt < 8; ++nt) {
                u64 packed =  (u64)f2bf(st[mf][nt][0])
                           | ((u64)f2bf(st[mf][nt][1]) << 16)
                           | ((u64)f2bf(st[mf][nt][2]) << 32)
                           | ((u64)f2bf(st[mf][nt][3]) << 48);
                int pc = (nt * 2 + (quad >> 1)) ^ (m & 7);
                *(u64*)(&Ks[m * 128 + pc * 8 + (quad & 1) * 4]) = packed;
            }
        }

        // PV: O[m][d] += P[m][j] * V[d][j]; own wave's P rows -> no barrier
        for (int ks = 0; ks < 4; ++ks) {
            bf16x8 pf[2];
            for (int mf = 0; mf < 2; ++mf) {
                int m = wid * 32 + mf * 16 + l15;
                pf[mf] = *(const bf16x8*)(&Ks[m * 128 + ((ks * 4 + quad) ^ (m & 7)) * 8]);
            }
            for (int dt = 0; dt < 8; ++dt) {
                int d = dt * 16 + l15;
                bf16x8 vf = *(const bf16x8*)(&Vs[d * 128 + ((ks * 4 + quad) ^ (d & 7)) * 8]);
                oacc[0][dt] = MFMA16(pf[0], vf, oacc[0][dt]);
                oacc[1][dt] = MFMA16(pf[1], vf, oacc[1][dt]);
            }
        }
    }

    for (int mf = 0; mf < 2; ++mf) {
        float inv = 1.f / lst[mf];
        float iv[4];
        for (int r = 0; r < 4; ++r) iv[r] = __shfl(inv, quad * 4 + r, 16);
        for (int r = 0; r < 4; ++r) {
            int m = i0 + wid * 32 + mf * 16 + quad * 4 + r;
            for (int dt = 0; dt < 8; ++dt) {
                int d = dt * 16 + l15;
                attnT[((size_t)b * LEN + m) * 512 + h * HD + d] =
                    f2bf(oacc[mf][dt][r] * iv[r]);
            }
        }
    }
}

// ---------------------------------------------------------------------------
extern "C" void kernel_launch(void* const* d_in, const int* in_sizes, int n_in,
                              void* d_out, int out_size, void* d_ws, size_t ws_size,
                              hipStream_t stream) {
    const float* x   = (const float*)d_in[0];
    const float* gns = (const float*)d_in[1];
    const float* gnb = (const float*)d_in[2];
    const float* wq  = (const float*)d_in[3];
    const float* bq  = (const float*)d_in[4];
    const float* wk  = (const float*)d_in[5];
    const float* bk  = (const float*)d_in[6];
    const float* wv  = (const float*)d_in[7];
    const float* bv  = (const float*)d_in[8];
    const float* wo  = (const float*)d_in[9];
    const float* bo  = (const float*)d_in[10];
    float* out = (float*)d_out;

    const size_t NEL = (size_t)BATCH * CCH * LEN;   // 8388608
    float* stats = (float*)d_ws;                     // 64 floats @ 0
    u16* wcat  = (u16*)((char*)d_ws + 256);          // 4 x 512x512 bf16 weights
    u16* hT    = wcat + 4 * 262144;                  // bf16 [B,L,C]; reused as attnT
    u16* qT    = hT + NEL;
    u16* kT    = qT + NEL;
    u16* vbuf  = kT + NEL;
    u16* attnT = hT;   // hT dead after gemm<1>; alias to save 16 MB

    const u16* wq_bf = wcat;
    const u16* wk_bf = wcat + 262144;
    const u16* wv_bf = wcat + 2 * 262144;
    const u16* wo_bf = wcat + 3 * 262144;

    hipMemsetAsync(d_ws, 0, 256, stream);
    wcvt_k<<<dim3(128, 4), 256, 0, stream>>>(wq, wk, wv, wo, wcat);
    gn_stats_k<<<256, 256, 0, stream>>>(x, stats);
    gn_apply_k<<<dim3(32, 8, 8), 256, 0, stream>>>(x, gns, gnb, stats, hT);
    gemm_k<0><<<dim3(8, 16, 8), 256, 0, stream>>>(hT, wq_bf, wk_bf, bq, bk, nullptr, qT, kT);
    gemm_k<1><<<dim3(16, 4, 8), 256, 0, stream>>>(wv_bf, hT, nullptr, bv, nullptr, nullptr, vbuf, nullptr);
    attn_k<<<dim3(16, 4, 8), 256, 0, stream>>>(qT, kT, vbuf, attnT);
    gemm_k<2><<<dim3(16, 4, 8), 256, 0, stream>>>(wo_bf, attnT, nullptr, bo, nullptr, x, out, nullptr);
}

// Round 6
// 276.645 us; speedup vs baseline: 1.8148x; 1.0486x over previous
//
#include <hip/hip_runtime.h>

// ---------------------------------------------------------------------------
// AttnBlock: GroupNorm -> QKV (1x1 conv) -> 4-head attention (L=2048, hd=128)
//            -> out proj -> residual.   B=8, C=512, L=2048, G=4, NH=4.
// Storage dtype: float32. Internal compute: bf16 MFMA, f32 accumulation.
// R6: hide the DMA drain. Attention: 64-key j-tiles, K/V double-buffered in
//     LDS (Ks[2]+Vs[2]=64KB), DMA(jt+1) issued at iter start, drained by the
//     mid-iter barrier after QK+softmax (~1.5k-cyc flight window). P overlays
//     the retired K buffer. GEMM K-loop: same dbuf, 1 barrier/iter.
//     Softmax: half-up P packing, ballot-skipped O rescale.
// ---------------------------------------------------------------------------

typedef unsigned short u16;
typedef unsigned int   u32;
typedef unsigned long long u64;
typedef __attribute__((ext_vector_type(8)))  short          bf16x8;  // MFMA A/B frag
typedef __attribute__((ext_vector_type(4)))  float          f32x4;   // MFMA C/D frag
typedef __attribute__((ext_vector_type(4)))  unsigned int   u32x4;   // 16B copy
typedef __attribute__((ext_vector_type(8)))  unsigned short u16x8;

#define MFMA16(a, b, c) __builtin_amdgcn_mfma_f32_16x16x32_bf16((a), (b), (c), 0, 0, 0)

__device__ __forceinline__ u16 f2bf(float f) {
    union { float f; unsigned int i; } cv;
    cv.f = f;
    unsigned int u = cv.i;
    u += 0x7fffu + ((u >> 16) & 1);   // RNE
    return (u16)(u >> 16);
}
__device__ __forceinline__ u32 fbits(float f) {
    union { float f; unsigned int i; } cv; cv.f = f; return cv.i;
}

// async 16B global->LDS (DMA; lands at lds_base + lane*16)
__device__ __forceinline__ void async16(const u16* g, u16* l) {
    __builtin_amdgcn_global_load_lds(
        (const __attribute__((address_space(1))) unsigned int*)g,
        (__attribute__((address_space(3))) unsigned int*)l, 16, 0, 0);
}

#define BATCH 8
#define CCH   512
#define LEN   2048
#define NGRP  4
#define NHEAD 4
#define HD    128
#define GSIZE (128 * 2048)   // elements per (b, group)

// ---------------------------------------------------------------------------
// 0) Convert the four 512x512 f32 weight matrices to bf16 (once per launch).
// ---------------------------------------------------------------------------
__global__ __launch_bounds__(256) void wcvt_k(const float* __restrict__ w0,
                                              const float* __restrict__ w1,
                                              const float* __restrict__ w2,
                                              const float* __restrict__ w3,
                                              u16* __restrict__ dst) {
    const int mat = blockIdx.y;
    const float* src = (mat == 0) ? w0 : (mat == 1) ? w1 : (mat == 2) ? w2 : w3;
    const size_t base = (size_t)blockIdx.x * 2048 + (size_t)threadIdx.x * 8;
    f32x4 a = *(const f32x4*)(src + base);
    f32x4 b = *(const f32x4*)(src + base + 4);
    u16x8 o;
    for (int u = 0; u < 4; ++u) { o[u] = f2bf(a[u]); o[u + 4] = f2bf(b[u]); }
    *(u16x8*)(dst + (size_t)mat * 262144 + base) = o;
}

// ---------------------------------------------------------------------------
// 1) GroupNorm partial stats (f32 input): 256 blocks, 16 channels of one (b,g).
// ---------------------------------------------------------------------------
__global__ __launch_bounds__(256) void gn_stats_k(const float* __restrict__ x,
                                                  float* __restrict__ stats) {
    const int bid   = blockIdx.x;       // 0..255
    const int grp   = bid >> 3;         // b*4+g
    const int chunk = bid & 7;          // 16-channel slab
    const int b = grp >> 2, g = grp & 3;
    const float* base = x + ((size_t)(b * CCH + g * 128 + chunk * 16)) * LEN;

    float s = 0.f, ss = 0.f;
    for (int i = 0; i < 32; ++i) {
        int cid = threadIdx.x + i * 256;          // 0..8191 chunks of 4
        f32x4 dv = *(const f32x4*)(base + (size_t)cid * 4);
        for (int u = 0; u < 4; ++u) { s += dv[u]; ss += dv[u] * dv[u]; }
    }
    for (int m = 1; m < 64; m <<= 1) {
        s  += __shfl_xor(s,  m, 64);
        ss += __shfl_xor(ss, m, 64);
    }
    __shared__ float red[8];
    int wid = threadIdx.x >> 6, lane = threadIdx.x & 63;
    if (lane == 0) { red[wid * 2] = s; red[wid * 2 + 1] = ss; }
    __syncthreads();
    if (threadIdx.x == 0) {
        float ts  = red[0] + red[2] + red[4] + red[6];
        float tss = red[1] + red[3] + red[5] + red[7];
        atomicAdd(&stats[grp * 2],     ts);
        atomicAdd(&stats[grp * 2 + 1], tss);
    }
}

// ---------------------------------------------------------------------------
// 2) GroupNorm apply + transpose: x[b,c,l] (f32) -> hT[b,l,c] (bf16).
//    64x64 tiles through LDS.
// ---------------------------------------------------------------------------
__global__ __launch_bounds__(256) void gn_apply_k(const float* __restrict__ x,
                                                  const float* __restrict__ gns,
                                                  const float* __restrict__ gnb,
                                                  const float* __restrict__ stats,
                                                  u16* __restrict__ hT) {
    __shared__ u16 Ts[64 * 72];
    const int b = blockIdx.z, c0 = blockIdx.y * 64, l0 = blockIdx.x * 64;
    const int g = c0 >> 7;
    const int tid = threadIdx.x;

    float sum   = stats[(b * NGRP + g) * 2];
    float sumsq = stats[(b * NGRP + g) * 2 + 1];
    const float invN = 1.f / (float)GSIZE;
    float mean = sum * invN;
    float var  = sumsq * invN - mean * mean;
    float rstd = rsqrtf(var + 1e-6f);

    for (int i = 0; i < 4; ++i) {
        int cid = tid + i * 256;          // 0..1023
        int row = cid >> 4, c4 = cid & 15; // row = channel in tile, col = c4*4
        int c = c0 + row;
        float sc = gns[c] * rstd;
        float bi = gnb[c] - mean * sc;
        f32x4 dv = *(const f32x4*)(x + ((size_t)(b * CCH + c)) * LEN + l0 + c4 * 4);
        for (int u = 0; u < 4; ++u)
            Ts[row * 72 + c4 * 4 + u] = f2bf(dv[u] * sc + bi);
    }
    __syncthreads();
    for (int i = 0; i < 2; ++i) {
        int cid = tid + i * 256;          // 0..511
        int lrow = cid >> 3, c8 = cid & 7;
        u16x8 ov;
        for (int u = 0; u < 8; ++u) ov[u] = Ts[(c8 * 8 + u) * 72 + lrow];
        *(u16x8*)(hT + ((size_t)b * LEN + l0 + lrow) * CCH + c0 + c8 * 8) = ov;
    }
}

// ---------------------------------------------------------------------------
// GEMM: D[m][n] = sum_k A[m][k]*B[n][k]; operands row-major [row, 512] bf16.
// MODE 0: A=hT[b] (m=l), B=wq_bf/wk_bf (n=o, N=1024) -> qT/kT (bf16) + bias
// MODE 1: A=wv_bf (m=o), B=hT[b] (n=l) -> v[b,c,l] (bf16) + bias
// MODE 2: A=wo_bf (m=o), B=attnT[b] (n=l) -> out[b,c,l] (f32) + bias + x
// 128x128x(K=512) tiles, BK=64, 4 waves (2x2), 64 f32 acc/lane.
// Staging: double-buffered global_load_lds (issue k+1 before compute k;
// single end-of-iter barrier drains with a full-MFMA flight window).
// ---------------------------------------------------------------------------
template <int MODE>
__global__ __launch_bounds__(256, 2) void gemm_k(const u16* __restrict__ A0,
                                                 const u16* __restrict__ B0,
                                                 const u16* __restrict__ B1,
                                                 const float* __restrict__ bias0,
                                                 const float* __restrict__ bias1,
                                                 const float* __restrict__ resid,
                                                 void* __restrict__ out0v,
                                                 u16* __restrict__ out1) {
    __shared__ u16 As[2][128 * 64];
    __shared__ u16 Bs[2][128 * 64];
    const int b  = blockIdx.z;
    const int n0 = blockIdx.x * 128;
    const int m0 = blockIdx.y * 128;
    const int tid = threadIdx.x;
    const int lane = tid & 63, wid = tid >> 6;
    const int quad = lane >> 4, l15 = lane & 15;
    const int wm = (wid & 1) * 64, wn = (wid >> 1) * 64;

    const u16* Arow;
    if constexpr (MODE == 0) Arow = A0 + ((size_t)b * LEN + m0) * 512;
    else                     Arow = A0 + (size_t)m0 * 512;

    const u16* Brow;
    int col0 = 0;
    if constexpr (MODE == 0) {
        if (n0 < 512) { Brow = B0 + (size_t)n0 * 512;         col0 = n0; }
        else          { Brow = B1 + (size_t)(n0 - 512) * 512;  col0 = n0 - 512; }
    } else {
        Brow = B0 + ((size_t)b * LEN + n0) * 512;
    }

    f32x4 acc[4][4] = {};
    const int srl = lane >> 3, scl = lane & 7;   // 8 rows/instr, chunk lane&7

    // prologue: stage k-tile 0 into buffer 0
#pragma unroll
    for (int i = 0; i < 4; ++i) {
        int rloc = wid * 32 + i * 8 + srl;
        int lc = scl ^ (rloc & 7);
        async16(Arow + (size_t)rloc * 512 + lc * 8, &As[0][(wid * 32 + i * 8) * 64]);
        async16(Brow + (size_t)rloc * 512 + lc * 8, &Bs[0][(wid * 32 + i * 8) * 64]);
    }
    __syncthreads();

    for (int kk = 0; kk < 8; ++kk) {
        const int p = kk & 1;
        if (kk < 7) {            // issue next tile's DMA; drained by end barrier
            const int k0n = (kk + 1) * 64;
#pragma unroll
            for (int i = 0; i < 4; ++i) {
                int rloc = wid * 32 + i * 8 + srl;
                int lc = scl ^ (rloc & 7);
                async16(Arow + (size_t)rloc * 512 + k0n + lc * 8,
                        &As[1 - p][(wid * 32 + i * 8) * 64]);
                async16(Brow + (size_t)rloc * 512 + k0n + lc * 8,
                        &Bs[1 - p][(wid * 32 + i * 8) * 64]);
            }
        }
#pragma unroll
        for (int ks = 0; ks < 2; ++ks) {
            bf16x8 af[4], bfr[4];
            for (int t = 0; t < 4; ++t) {
                int ra = wm + t * 16 + l15, rb = wn + t * 16 + l15;
                af[t]  = *(const bf16x8*)(&As[p][ra * 64 + (((ks * 4 + quad) ^ (ra & 7))) * 8]);
                bfr[t] = *(const bf16x8*)(&Bs[p][rb * 64 + (((ks * 4 + quad) ^ (rb & 7))) * 8]);
            }
            for (int mt = 0; mt < 4; ++mt)
                for (int nt = 0; nt < 4; ++nt)
                    acc[mt][nt] = MFMA16(af[mt], bfr[nt], acc[mt][nt]);
        }
        __syncthreads();   // reads of [p] done; DMA(kk+1) drained (flew over MFMA)
    }

    if constexpr (MODE == 0) {
        const float* biasp = (n0 < 512) ? (bias0 + col0) : (bias1 + col0);
        u16* outp = (n0 < 512) ? (u16*)out0v : out1;
        for (int nt = 0; nt < 4; ++nt) {
            int nl = wn + nt * 16 + l15;
            float bv_ = biasp[nl];
            for (int mt = 0; mt < 4; ++mt)
                for (int r = 0; r < 4; ++r) {
                    int ml = wm + mt * 16 + quad * 4 + r;
                    size_t idx = ((size_t)b * LEN + m0 + ml) * 512 + col0 + nl;
                    outp[idx] = f2bf(acc[mt][nt][r] + bv_);
                }
        }
    } else {
        for (int mt = 0; mt < 4; ++mt)
            for (int r = 0; r < 4; ++r) {
                int ml = wm + mt * 16 + quad * 4 + r;
                float bv_ = bias0[m0 + ml];
                for (int nt = 0; nt < 4; ++nt) {
                    int nl = wn + nt * 16 + l15;
                    size_t idx = ((size_t)(b * 512 + m0 + ml)) * LEN + n0 + nl;
                    float val = acc[mt][nt][r] + bv_;
                    if constexpr (MODE == 2) {
                        ((float*)out0v)[idx] = val + resid[idx];
                    } else {
                        ((u16*)out0v)[idx] = f2bf(val);
                    }
                }
            }
    }
}

// ---------------------------------------------------------------------------
// Flash attention v5: S^T form, 64-key j-tiles, K/V LDS double-buffered.
// Block = (b, h, 128-query tile), 4 waves; wave owns 32 q-rows (2 m-frags).
// LDS: Ks[2][64x128] + Vs[2][128x64] = 64 KB. XOR-swizzled 16B chunks.
// Iter jt: issue DMA(jt+1) -> alt buffers; QK^T from Ks[p] (32 MFMA);
// online softmax (per-lane state); mid-barrier (drains DMA(jt+1), flight
// window = QK+softmax); P overlays Ks[p] (8 ds_write_b64, half-up rounding);
// PV from Vs[p]+P (32 MFMA); end barrier (pure sync). 32 iters.
// ---------------------------------------------------------------------------
__global__ __launch_bounds__(256, 2) void attn_k(const u16* __restrict__ qT,
                                                 const u16* __restrict__ kT,
                                                 const u16* __restrict__ v,
                                                 u16* __restrict__ attnT) {
    __shared__ u16 Ks[2][64 * 128];   // K tile; retired buffer doubles as P[128x64]
    __shared__ u16 Vs[2][128 * 64];
    const int b = blockIdx.z, h = blockIdx.y;
    const int i0 = blockIdx.x * 128;
    const int tid = threadIdx.x, lane = tid & 63, wid = tid >> 6;
    const int quad = lane >> 4, l15 = lane & 15;

    // Q B-frags for this wave's 32 m-rows (mf=0,1)
    bf16x8 qa[2][4];
    for (int mf = 0; mf < 2; ++mf)
        for (int ks = 0; ks < 4; ++ks) {
            int m = i0 + wid * 32 + mf * 16 + l15;
            qa[mf][ks] = *(const bf16x8*)(qT + ((size_t)b * LEN + m) * 512 + h * HD +
                                          ks * 32 + quad * 8);
        }

    float mst[2] = {-3.0e38f, -3.0e38f}, lst[2] = {0.f, 0.f};
    f32x4 oacc[2][8] = {};

    const float SL2E = 0.08838834764831845f * 1.4426950408889634f; // scale*log2e

    // staging geometry
    const int srwK = lane >> 4, scK = lane & 15;  // K: 4 rows/instr, 16 chunks/row
    const int srwV = lane >> 3, scV = lane & 7;   // V: 8 rows/instr,  8 chunks/row
    const u16* kbase = kT + ((size_t)b * LEN) * 512 + h * HD;
    const u16* vbase = v + ((size_t)(b * CCH + h * HD)) * LEN;

    // prologue: stage tile 0 into buffer 0
#pragma unroll
    for (int i = 0; i < 4; ++i) {
        int rk = wid * 16 + i * 4 + srwK;
        int lck = scK ^ (rk & 7);
        async16(kbase + (size_t)rk * 512 + lck * 8, &Ks[0][(wid * 16 + i * 4) * 128]);
        int rv = wid * 32 + i * 8 + srwV;
        int lcv = scV ^ (rv & 7);
        async16(vbase + (size_t)rv * LEN + lcv * 8, &Vs[0][(wid * 32 + i * 8) * 64]);
    }
    __syncthreads();

    for (int jt = 0; jt < 32; ++jt) {
        const int p = jt & 1;
        const int j0 = jt * 64;

        // issue DMA(jt+1) into alternate buffers; drained at mid-barrier
        if (jt < 31) {
            const int j0n = j0 + 64;
#pragma unroll
            for (int i = 0; i < 4; ++i) {
                int rk = wid * 16 + i * 4 + srwK;
                int lck = scK ^ (rk & 7);
                async16(kbase + (size_t)(j0n + rk) * 512 + lck * 8,
                        &Ks[1 - p][(wid * 16 + i * 4) * 128]);
                int rv = wid * 32 + i * 8 + srwV;
                int lcv = scV ^ (rv & 7);
                async16(vbase + (size_t)rv * LEN + j0n + lcv * 8,
                        &Vs[1 - p][(wid * 32 + i * 8) * 64]);
            }
        }

        // S^T: st[mf][jtn] rows j = jtn*16+quad*4+r, cols m = wid*32+mf*16+l15
        f32x4 st[2][4] = {};
#pragma unroll
        for (int jtn = 0; jtn < 4; ++jtn) {
            int r = jtn * 16 + l15;
            for (int ks = 0; ks < 4; ++ks) {
                bf16x8 kf = *(const bf16x8*)(&Ks[p][r * 128 + ((ks * 4 + quad) ^ (r & 7)) * 8]);
                st[0][jtn] = MFMA16(kf, qa[0][ks], st[0][jtn]);
                st[1][jtn] = MFMA16(kf, qa[1][ks], st[1][jtn]);
            }
        }

        // online softmax per mf; state per lane (m = l15), quad-replicated
        float alpha2[2];
#pragma unroll
        for (int mf = 0; mf < 2; ++mf) {
            float rm = -3.0e38f;
            for (int jtn = 0; jtn < 4; ++jtn)
                for (int r = 0; r < 4; ++r) rm = fmaxf(rm, st[mf][jtn][r]);
            rm *= SL2E;
            rm = fmaxf(rm, __shfl_xor(rm, 16, 64));
            rm = fmaxf(rm, __shfl_xor(rm, 32, 64));
            float mnew  = fmaxf(mst[mf], rm);
            float alpha = __builtin_amdgcn_exp2f(mst[mf] - mnew);
            mst[mf] = mnew;
            float rs = 0.f;
            for (int jtn = 0; jtn < 4; ++jtn)
                for (int r = 0; r < 4; ++r) {
                    float pv_ = __builtin_amdgcn_exp2f(st[mf][jtn][r] * SL2E - mnew);
                    st[mf][jtn][r] = pv_;
                    rs += pv_;
                }
            rs += __shfl_xor(rs, 16, 64);
            rs += __shfl_xor(rs, 32, 64);
            lst[mf] = lst[mf] * alpha + rs;
            alpha2[mf] = alpha;
        }
        // rescale O only if some lane actually changed max (late iters skip)
        if (__ballot(alpha2[0] != 1.0f || alpha2[1] != 1.0f) != 0ull) {
#pragma unroll
            for (int mf = 0; mf < 2; ++mf) {
                float av[4];
                for (int r = 0; r < 4; ++r) av[r] = __shfl(alpha2[mf], quad * 4 + r, 16);
                for (int dt = 0; dt < 8; ++dt)
                    for (int r = 0; r < 4; ++r) oacc[mf][dt][r] *= av[r];
            }
        }

        // all waves' QK reads of Ks[p] done; DMA(jt+1) drained here too
        __syncthreads();

        // P[m][j] (bf16, half-up) overlays Ks[p] as [128][64], swizzled
#pragma unroll
        for (int mf = 0; mf < 2; ++mf) {
            int m = wid * 32 + mf * 16 + l15;
            for (int jtn = 0; jtn < 4; ++jtn) {
                u64 packed =  (u64)((fbits(st[mf][jtn][0]) + 0x8000u) >> 16)
                           | ((u64)((fbits(st[mf][jtn][1]) + 0x8000u) >> 16) << 16)
                           | ((u64)((fbits(st[mf][jtn][2]) + 0x8000u) >> 16) << 32)
                           | ((u64)((fbits(st[mf][jtn][3]) + 0x8000u) >> 16) << 48);
                int pc = (jtn * 2 + (quad >> 1)) ^ (m & 7);
                *(u64*)(&Ks[p][m * 64 + pc * 8 + (quad & 1) * 4]) = packed;
            }
        }

        // PV: O[m][d] += P[m][j] * V[d][j]; own wave's P rows -> no barrier
#pragma unroll
        for (int ks = 0; ks < 2; ++ks) {
            bf16x8 pf[2];
            for (int mf = 0; mf < 2; ++mf) {
                int m = wid * 32 + mf * 16 + l15;
                pf[mf] = *(const bf16x8*)(&Ks[p][m * 64 + ((ks * 4 + quad) ^ (m & 7)) * 8]);
            }
            for (int dt = 0; dt < 8; ++dt) {
                int d = dt * 16 + l15;
                bf16x8 vf = *(const bf16x8*)(&Vs[p][d * 64 + ((ks * 4 + quad) ^ (d & 7)) * 8]);
                oacc[0][dt] = MFMA16(pf[0], vf, oacc[0][dt]);
                oacc[1][dt] = MFMA16(pf[1], vf, oacc[1][dt]);
            }
        }

        __syncthreads();   // PV reads of [p] done before iter jt+1 re-stages [p]
    }

    for (int mf = 0; mf < 2; ++mf) {
        float inv = 1.f / lst[mf];
        float iv[4];
        for (int r = 0; r < 4; ++r) iv[r] = __shfl(inv, quad * 4 + r, 16);
        for (int r = 0; r < 4; ++r) {
            int m = i0 + wid * 32 + mf * 16 + quad * 4 + r;
            for (int dt = 0; dt < 8; ++dt) {
                int d = dt * 16 + l15;
                attnT[((size_t)b * LEN + m) * 512 + h * HD + d] =
                    f2bf(oacc[mf][dt][r] * iv[r]);
            }
        }
    }
}

// ---------------------------------------------------------------------------
extern "C" void kernel_launch(void* const* d_in, const int* in_sizes, int n_in,
                              void* d_out, int out_size, void* d_ws, size_t ws_size,
                              hipStream_t stream) {
    const float* x   = (const float*)d_in[0];
    const float* gns = (const float*)d_in[1];
    const float* gnb = (const float*)d_in[2];
    const float* wq  = (const float*)d_in[3];
    const float* bq  = (const float*)d_in[4];
    const float* wk  = (const float*)d_in[5];
    const float* bk  = (const float*)d_in[6];
    const float* wv  = (const float*)d_in[7];
    const float* bv  = (const float*)d_in[8];
    const float* wo  = (const float*)d_in[9];
    const float* bo  = (const float*)d_in[10];
    float* out = (float*)d_out;

    const size_t NEL = (size_t)BATCH * CCH * LEN;   // 8388608
    float* stats = (float*)d_ws;                     // 64 floats @ 0
    u16* wcat  = (u16*)((char*)d_ws + 256);          // 4 x 512x512 bf16 weights
    u16* hT    = wcat + 4 * 262144;                  // bf16 [B,L,C]; reused as attnT
    u16* qT    = hT + NEL;
    u16* kT    = qT + NEL;
    u16* vbuf  = kT + NEL;
    u16* attnT = hT;   // hT dead after gemm<1>; alias to save 16 MB

    const u16* wq_bf = wcat;
    const u16* wk_bf = wcat + 262144;
    const u16* wv_bf = wcat + 2 * 262144;
    const u16* wo_bf = wcat + 3 * 262144;

    hipMemsetAsync(d_ws, 0, 256, stream);
    wcvt_k<<<dim3(128, 4), 256, 0, stream>>>(wq, wk, wv, wo, wcat);
    gn_stats_k<<<256, 256, 0, stream>>>(x, stats);
    gn_apply_k<<<dim3(32, 8, 8), 256, 0, stream>>>(x, gns, gnb, stats, hT);
    gemm_k<0><<<dim3(8, 16, 8), 256, 0, stream>>>(hT, wq_bf, wk_bf, bq, bk, nullptr, qT, kT);
    gemm_k<1><<<dim3(16, 4, 8), 256, 0, stream>>>(wv_bf, hT, nullptr, bv, nullptr, nullptr, vbuf, nullptr);
    attn_k<<<dim3(16, 4, 8), 256, 0, stream>>>(qT, kT, vbuf, attnT);
    gemm_k<2><<<dim3(16, 4, 8), 256, 0, stream>>>(wo_bf, attnT, nullptr, bo, nullptr, x, out, nullptr);
}

// Round 7
// 275.332 us; speedup vs baseline: 1.8235x; 1.0048x over previous
//
#include <hip/hip_runtime.h>

// ---------------------------------------------------------------------------
// AttnBlock: GroupNorm -> QKV (1x1 conv) -> 4-head attention (L=2048, hd=128)
//            -> out proj -> residual.   B=8, C=512, L=2048, G=4, NH=4.
// Storage dtype: float32. Internal compute: bf16 MFMA, f32 accumulation.
// R7: attention K-loop rebuilt AITER-style: raw s_barrier + partial
//     s_waitcnt vmcnt(12)/vmcnt(8) -- the distance-1 K/V prefetch is NEVER
//     drained to zero, so each tile has a full iteration of flight time
//     (vs R6 where __syncthreads vmcnt(0)-drained the just-issued DMA).
//     DMA global addresses hoisted to loop-carried pointers (~150 VALU/iter
//     saved). GEMM/GN kernels unchanged from R6.
// ---------------------------------------------------------------------------

typedef unsigned short u16;
typedef unsigned int   u32;
typedef unsigned long long u64;
typedef __attribute__((ext_vector_type(8)))  short          bf16x8;  // MFMA A/B frag
typedef __attribute__((ext_vector_type(4)))  float          f32x4;   // MFMA C/D frag
typedef __attribute__((ext_vector_type(4)))  unsigned int   u32x4;   // 16B copy
typedef __attribute__((ext_vector_type(8)))  unsigned short u16x8;

#define MFMA16(a, b, c) __builtin_amdgcn_mfma_f32_16x16x32_bf16((a), (b), (c), 0, 0, 0)

// s_waitcnt simm16: vmcnt[3:0]|[15:14], expcnt[6:4], lgkmcnt[11:8]
#define WAIT_VM12        3964   // vm<=12, exp/lgkm untouched
#define WAIT_VM8_LGKM0    120   // vm<=8, lgkm=0
#define BARRIER() __builtin_amdgcn_s_barrier()

__device__ __forceinline__ u16 f2bf(float f) {
    union { float f; unsigned int i; } cv;
    cv.f = f;
    unsigned int u = cv.i;
    u += 0x7fffu + ((u >> 16) & 1);   // RNE
    return (u16)(u >> 16);
}
__device__ __forceinline__ u32 fbits(float f) {
    union { float f; unsigned int i; } cv; cv.f = f; return cv.i;
}

// async 16B global->LDS (DMA; lands at lds_base + lane*16)
__device__ __forceinline__ void async16(const u16* g, u16* l) {
    __builtin_amdgcn_global_load_lds(
        (const __attribute__((address_space(1))) unsigned int*)g,
        (__attribute__((address_space(3))) unsigned int*)l, 16, 0, 0);
}

#define BATCH 8
#define CCH   512
#define LEN   2048
#define NGRP  4
#define NHEAD 4
#define HD    128
#define GSIZE (128 * 2048)   // elements per (b, group)

// ---------------------------------------------------------------------------
// 0) Convert the four 512x512 f32 weight matrices to bf16 (once per launch).
// ---------------------------------------------------------------------------
__global__ __launch_bounds__(256) void wcvt_k(const float* __restrict__ w0,
                                              const float* __restrict__ w1,
                                              const float* __restrict__ w2,
                                              const float* __restrict__ w3,
                                              u16* __restrict__ dst) {
    const int mat = blockIdx.y;
    const float* src = (mat == 0) ? w0 : (mat == 1) ? w1 : (mat == 2) ? w2 : w3;
    const size_t base = (size_t)blockIdx.x * 2048 + (size_t)threadIdx.x * 8;
    f32x4 a = *(const f32x4*)(src + base);
    f32x4 b = *(const f32x4*)(src + base + 4);
    u16x8 o;
    for (int u = 0; u < 4; ++u) { o[u] = f2bf(a[u]); o[u + 4] = f2bf(b[u]); }
    *(u16x8*)(dst + (size_t)mat * 262144 + base) = o;
}

// ---------------------------------------------------------------------------
// 1) GroupNorm partial stats (f32 input): 256 blocks, 16 channels of one (b,g).
// ---------------------------------------------------------------------------
__global__ __launch_bounds__(256) void gn_stats_k(const float* __restrict__ x,
                                                  float* __restrict__ stats) {
    const int bid   = blockIdx.x;       // 0..255
    const int grp   = bid >> 3;         // b*4+g
    const int chunk = bid & 7;          // 16-channel slab
    const int b = grp >> 2, g = grp & 3;
    const float* base = x + ((size_t)(b * CCH + g * 128 + chunk * 16)) * LEN;

    float s = 0.f, ss = 0.f;
    for (int i = 0; i < 32; ++i) {
        int cid = threadIdx.x + i * 256;          // 0..8191 chunks of 4
        f32x4 dv = *(const f32x4*)(base + (size_t)cid * 4);
        for (int u = 0; u < 4; ++u) { s += dv[u]; ss += dv[u] * dv[u]; }
    }
    for (int m = 1; m < 64; m <<= 1) {
        s  += __shfl_xor(s,  m, 64);
        ss += __shfl_xor(ss, m, 64);
    }
    __shared__ float red[8];
    int wid = threadIdx.x >> 6, lane = threadIdx.x & 63;
    if (lane == 0) { red[wid * 2] = s; red[wid * 2 + 1] = ss; }
    __syncthreads();
    if (threadIdx.x == 0) {
        float ts  = red[0] + red[2] + red[4] + red[6];
        float tss = red[1] + red[3] + red[5] + red[7];
        atomicAdd(&stats[grp * 2],     ts);
        atomicAdd(&stats[grp * 2 + 1], tss);
    }
}

// ---------------------------------------------------------------------------
// 2) GroupNorm apply + transpose: x[b,c,l] (f32) -> hT[b,l,c] (bf16).
//    64x64 tiles through LDS.
// ---------------------------------------------------------------------------
__global__ __launch_bounds__(256) void gn_apply_k(const float* __restrict__ x,
                                                  const float* __restrict__ gns,
                                                  const float* __restrict__ gnb,
                                                  const float* __restrict__ stats,
                                                  u16* __restrict__ hT) {
    __shared__ u16 Ts[64 * 72];
    const int b = blockIdx.z, c0 = blockIdx.y * 64, l0 = blockIdx.x * 64;
    const int g = c0 >> 7;
    const int tid = threadIdx.x;

    float sum   = stats[(b * NGRP + g) * 2];
    float sumsq = stats[(b * NGRP + g) * 2 + 1];
    const float invN = 1.f / (float)GSIZE;
    float mean = sum * invN;
    float var  = sumsq * invN - mean * mean;
    float rstd = rsqrtf(var + 1e-6f);

    for (int i = 0; i < 4; ++i) {
        int cid = tid + i * 256;          // 0..1023
        int row = cid >> 4, c4 = cid & 15; // row = channel in tile, col = c4*4
        int c = c0 + row;
        float sc = gns[c] * rstd;
        float bi = gnb[c] - mean * sc;
        f32x4 dv = *(const f32x4*)(x + ((size_t)(b * CCH + c)) * LEN + l0 + c4 * 4);
        for (int u = 0; u < 4; ++u)
            Ts[row * 72 + c4 * 4 + u] = f2bf(dv[u] * sc + bi);
    }
    __syncthreads();
    for (int i = 0; i < 2; ++i) {
        int cid = tid + i * 256;          // 0..511
        int lrow = cid >> 3, c8 = cid & 7;
        u16x8 ov;
        for (int u = 0; u < 8; ++u) ov[u] = Ts[(c8 * 8 + u) * 72 + lrow];
        *(u16x8*)(hT + ((size_t)b * LEN + l0 + lrow) * CCH + c0 + c8 * 8) = ov;
    }
}

// ---------------------------------------------------------------------------
// GEMM: D[m][n] = sum_k A[m][k]*B[n][k]; operands row-major [row, 512] bf16.
// MODE 0: A=hT[b] (m=l), B=wq_bf/wk_bf (n=o, N=1024) -> qT/kT (bf16) + bias
// MODE 1: A=wv_bf (m=o), B=hT[b] (n=l) -> v[b,c,l] (bf16) + bias
// MODE 2: A=wo_bf (m=o), B=attnT[b] (n=l) -> out[b,c,l] (f32) + bias + x
// 128x128x(K=512) tiles, BK=64, 4 waves (2x2), 64 f32 acc/lane.
// Staging: double-buffered global_load_lds (issue k+1 before compute k).
// ---------------------------------------------------------------------------
template <int MODE>
__global__ __launch_bounds__(256, 2) void gemm_k(const u16* __restrict__ A0,
                                                 const u16* __restrict__ B0,
                                                 const u16* __restrict__ B1,
                                                 const float* __restrict__ bias0,
                                                 const float* __restrict__ bias1,
                                                 const float* __restrict__ resid,
                                                 void* __restrict__ out0v,
                                                 u16* __restrict__ out1) {
    __shared__ u16 As[2][128 * 64];
    __shared__ u16 Bs[2][128 * 64];
    const int b  = blockIdx.z;
    const int n0 = blockIdx.x * 128;
    const int m0 = blockIdx.y * 128;
    const int tid = threadIdx.x;
    const int lane = tid & 63, wid = tid >> 6;
    const int quad = lane >> 4, l15 = lane & 15;
    const int wm = (wid & 1) * 64, wn = (wid >> 1) * 64;

    const u16* Arow;
    if constexpr (MODE == 0) Arow = A0 + ((size_t)b * LEN + m0) * 512;
    else                     Arow = A0 + (size_t)m0 * 512;

    const u16* Brow;
    int col0 = 0;
    if constexpr (MODE == 0) {
        if (n0 < 512) { Brow = B0 + (size_t)n0 * 512;         col0 = n0; }
        else          { Brow = B1 + (size_t)(n0 - 512) * 512;  col0 = n0 - 512; }
    } else {
        Brow = B0 + ((size_t)b * LEN + n0) * 512;
    }

    f32x4 acc[4][4] = {};
    const int srl = lane >> 3, scl = lane & 7;   // 8 rows/instr, chunk lane&7

    // prologue: stage k-tile 0 into buffer 0
#pragma unroll
    for (int i = 0; i < 4; ++i) {
        int rloc = wid * 32 + i * 8 + srl;
        int lc = scl ^ (rloc & 7);
        async16(Arow + (size_t)rloc * 512 + lc * 8, &As[0][(wid * 32 + i * 8) * 64]);
        async16(Brow + (size_t)rloc * 512 + lc * 8, &Bs[0][(wid * 32 + i * 8) * 64]);
    }
    __syncthreads();

    for (int kk = 0; kk < 8; ++kk) {
        const int p = kk & 1;
        if (kk < 7) {            // issue next tile's DMA; drained by end barrier
            const int k0n = (kk + 1) * 64;
#pragma unroll
            for (int i = 0; i < 4; ++i) {
                int rloc = wid * 32 + i * 8 + srl;
                int lc = scl ^ (rloc & 7);
                async16(Arow + (size_t)rloc * 512 + k0n + lc * 8,
                        &As[1 - p][(wid * 32 + i * 8) * 64]);
                async16(Brow + (size_t)rloc * 512 + k0n + lc * 8,
                        &Bs[1 - p][(wid * 32 + i * 8) * 64]);
            }
        }
#pragma unroll
        for (int ks = 0; ks < 2; ++ks) {
            bf16x8 af[4], bfr[4];
            for (int t = 0; t < 4; ++t) {
                int ra = wm + t * 16 + l15, rb = wn + t * 16 + l15;
                af[t]  = *(const bf16x8*)(&As[p][ra * 64 + (((ks * 4 + quad) ^ (ra & 7))) * 8]);
                bfr[t] = *(const bf16x8*)(&Bs[p][rb * 64 + (((ks * 4 + quad) ^ (rb & 7))) * 8]);
            }
            for (int mt = 0; mt < 4; ++mt)
                for (int nt = 0; nt < 4; ++nt)
                    acc[mt][nt] = MFMA16(af[mt], bfr[nt], acc[mt][nt]);
        }
        __syncthreads();   // reads of [p] done; DMA(kk+1) drained (flew over MFMA)
    }

    if constexpr (MODE == 0) {
        const float* biasp = (n0 < 512) ? (bias0 + col0) : (bias1 + col0);
        u16* outp = (n0 < 512) ? (u16*)out0v : out1;
        for (int nt = 0; nt < 4; ++nt) {
            int nl = wn + nt * 16 + l15;
            float bv_ = biasp[nl];
            for (int mt = 0; mt < 4; ++mt)
                for (int r = 0; r < 4; ++r) {
                    int ml = wm + mt * 16 + quad * 4 + r;
                    size_t idx = ((size_t)b * LEN + m0 + ml) * 512 + col0 + nl;
                    outp[idx] = f2bf(acc[mt][nt][r] + bv_);
                }
        }
    } else {
        for (int mt = 0; mt < 4; ++mt)
            for (int r = 0; r < 4; ++r) {
                int ml = wm + mt * 16 + quad * 4 + r;
                float bv_ = bias0[m0 + ml];
                for (int nt = 0; nt < 4; ++nt) {
                    int nl = wn + nt * 16 + l15;
                    size_t idx = ((size_t)(b * 512 + m0 + ml)) * LEN + n0 + nl;
                    float val = acc[mt][nt][r] + bv_;
                    if constexpr (MODE == 2) {
                        ((float*)out0v)[idx] = val + resid[idx];
                    } else {
                        ((u16*)out0v)[idx] = f2bf(val);
                    }
                }
            }
    }
}

// ---------------------------------------------------------------------------
// Flash attention v6: S^T form, 64-key j-tiles, K/V LDS double-buffered,
// AITER-style partial-vmcnt pipeline (prefetch never drained to zero).
// Per iter: issue K(jt+1)/V(jt+1); waitcnt vm<=12 (K(jt) landed, issued a
// full iter ago); barrier; QK+softmax; waitcnt vm<=8 lgkm 0 (V(jt) landed);
// barrier; P overlays Ks[p]; PV; waitcnt lgkm 0; barrier.
// Last iter re-stages tile 31 (valid addrs, never read) to keep counts
// uniform. DMA addresses are loop-carried pointers.
// ---------------------------------------------------------------------------
__global__ __launch_bounds__(256, 2) void attn_k(const u16* __restrict__ qT,
                                                 const u16* __restrict__ kT,
                                                 const u16* __restrict__ v,
                                                 u16* __restrict__ attnT) {
    __shared__ u16 Ks[2][64 * 128];   // K tile; retired buffer doubles as P[128x64]
    __shared__ u16 Vs[2][128 * 64];
    const int b = blockIdx.z, h = blockIdx.y;
    const int i0 = blockIdx.x * 128;
    const int tid = threadIdx.x, lane = tid & 63, wid = tid >> 6;
    const int quad = lane >> 4, l15 = lane & 15;

    // Q B-frags for this wave's 32 m-rows (mf=0,1)
    bf16x8 qa[2][4];
    for (int mf = 0; mf < 2; ++mf)
        for (int ks = 0; ks < 4; ++ks) {
            int m = i0 + wid * 32 + mf * 16 + l15;
            qa[mf][ks] = *(const bf16x8*)(qT + ((size_t)b * LEN + m) * 512 + h * HD +
                                          ks * 32 + quad * 8);
        }

    float mst[2] = {-3.0e38f, -3.0e38f}, lst[2] = {0.f, 0.f};
    f32x4 oacc[2][8] = {};

    const float SL2E = 0.08838834764831845f * 1.4426950408889634f; // scale*log2e

    // staging geometry + loop-carried global pointers (advance by one j-tile)
    const int srwK = lane >> 4, scK = lane & 15;  // K: 4 rows/instr, 16 chunks/row
    const int srwV = lane >> 3, scV = lane & 7;   // V: 8 rows/instr,  8 chunks/row
    const u16* kbase = kT + ((size_t)b * LEN) * 512 + h * HD;
    const u16* vbase = v + ((size_t)(b * CCH + h * HD)) * LEN;

    const u16* kgp[4];
    const u16* vgp[4];
    int krow[4], vrow[4];
#pragma unroll
    for (int i = 0; i < 4; ++i) {
        int rk = wid * 16 + i * 4 + srwK;
        krow[i] = wid * 16 + i * 4;
        kgp[i] = kbase + (size_t)rk * 512 + (scK ^ (rk & 7)) * 8;
        int rv = wid * 32 + i * 8 + srwV;
        vrow[i] = wid * 32 + i * 8;
        vgp[i] = vbase + (size_t)rv * LEN + (scV ^ (rv & 7)) * 8;
    }

    // prologue: stage tile 0 into buffer 0, advance pointers to tile 1
#pragma unroll
    for (int i = 0; i < 4; ++i) {
        async16(kgp[i], &Ks[0][krow[i] * 128]);
        async16(vgp[i], &Vs[0][vrow[i] * 64]);
        kgp[i] += 64 * 512;
        vgp[i] += 64;
    }

    for (int jt = 0; jt < 32; ++jt) {
        const int p = jt & 1;

        // issue next tile's DMA into [1-p] (jt=31: harmless re-stage of t31)
#pragma unroll
        for (int i = 0; i < 4; ++i) {
            async16(kgp[i], &Ks[1 - p][krow[i] * 128]);
            async16(vgp[i], &Vs[1 - p][vrow[i] * 64]);
        }
        if (jt < 30) {
#pragma unroll
            for (int i = 0; i < 4; ++i) { kgp[i] += 64 * 512; vgp[i] += 64; }
        }

        __builtin_amdgcn_s_waitcnt(WAIT_VM12);   // K(jt) landed (mine)
        BARRIER();                               // K(jt) landed (all waves)

        // S^T: st[mf][jtn] rows j = jtn*16+quad*4+r, cols m = wid*32+mf*16+l15
        f32x4 st[2][4] = {};
#pragma unroll
        for (int jtn = 0; jtn < 4; ++jtn) {
            int r = jtn * 16 + l15;
            for (int ks = 0; ks < 4; ++ks) {
                bf16x8 kf = *(const bf16x8*)(&Ks[p][r * 128 + ((ks * 4 + quad) ^ (r & 7)) * 8]);
                st[0][jtn] = MFMA16(kf, qa[0][ks], st[0][jtn]);
                st[1][jtn] = MFMA16(kf, qa[1][ks], st[1][jtn]);
            }
        }

        // online softmax per mf; state per lane (m = l15), quad-replicated
        float alpha2[2];
#pragma unroll
        for (int mf = 0; mf < 2; ++mf) {
            float rm = -3.0e38f;
            for (int jtn = 0; jtn < 4; ++jtn)
                for (int r = 0; r < 4; ++r) rm = fmaxf(rm, st[mf][jtn][r]);
            rm *= SL2E;
            rm = fmaxf(rm, __shfl_xor(rm, 16, 64));
            rm = fmaxf(rm, __shfl_xor(rm, 32, 64));
            float mnew  = fmaxf(mst[mf], rm);
            float alpha = __builtin_amdgcn_exp2f(mst[mf] - mnew);
            mst[mf] = mnew;
            float rs = 0.f;
            for (int jtn = 0; jtn < 4; ++jtn)
                for (int r = 0; r < 4; ++r) {
                    float pv_ = __builtin_amdgcn_exp2f(st[mf][jtn][r] * SL2E - mnew);
                    st[mf][jtn][r] = pv_;
                    rs += pv_;
                }
            rs += __shfl_xor(rs, 16, 64);
            rs += __shfl_xor(rs, 32, 64);
            lst[mf] = lst[mf] * alpha + rs;
            alpha2[mf] = alpha;
        }
        // rescale O only if some lane actually changed max (late iters skip)
        if (__ballot(alpha2[0] != 1.0f || alpha2[1] != 1.0f) != 0ull) {
#pragma unroll
            for (int mf = 0; mf < 2; ++mf) {
                float av[4];
                for (int r = 0; r < 4; ++r) av[r] = __shfl(alpha2[mf], quad * 4 + r, 16);
                for (int dt = 0; dt < 8; ++dt)
                    for (int r = 0; r < 4; ++r) oacc[mf][dt][r] *= av[r];
            }
        }

        __builtin_amdgcn_s_waitcnt(WAIT_VM8_LGKM0);  // V(jt) landed; QK reads retired
        BARRIER();                                   // all waves: V ready, Ks[p] free

        // P[m][j] (bf16, half-up) overlays Ks[p] as [128][64], swizzled
#pragma unroll
        for (int mf = 0; mf < 2; ++mf) {
            int m = wid * 32 + mf * 16 + l15;
            for (int jtn = 0; jtn < 4; ++jtn) {
                u64 packed =  (u64)((fbits(st[mf][jtn][0]) + 0x8000u) >> 16)
                           | ((u64)((fbits(st[mf][jtn][1]) + 0x8000u) >> 16) << 16)
                           | ((u64)((fbits(st[mf][jtn][2]) + 0x8000u) >> 16) << 32)
                           | ((u64)((fbits(st[mf][jtn][3]) + 0x8000u) >> 16) << 48);
                int pc = (jtn * 2 + (quad >> 1)) ^ (m & 7);
                *(u64*)(&Ks[p][m * 64 + pc * 8 + (quad & 1) * 4]) = packed;
            }
        }

        // PV: O[m][d] += P[m][j] * V[d][j]; own wave's P rows -> no barrier
#pragma unroll
        for (int ks = 0; ks < 2; ++ks) {
            bf16x8 pf[2];
            for (int mf = 0; mf < 2; ++mf) {
                int m = wid * 32 + mf * 16 + l15;
                pf[mf] = *(const bf16x8*)(&Ks[p][m * 64 + ((ks * 4 + quad) ^ (m & 7)) * 8]);
            }
            for (int dt = 0; dt < 8; ++dt) {
                int d = dt * 16 + l15;
                bf16x8 vf = *(const bf16x8*)(&Vs[p][d * 64 + ((ks * 4 + quad) ^ (d & 7)) * 8]);
                oacc[0][dt] = MFMA16(pf[0], vf, oacc[0][dt]);
                oacc[1][dt] = MFMA16(pf[1], vf, oacc[1][dt]);
            }
        }

        __builtin_amdgcn_s_waitcnt(WAIT_VM8_LGKM0);  // DS retired; prefetch stays out
        BARRIER();                                   // PV done before [p] restage
    }

    for (int mf = 0; mf < 2; ++mf) {
        float inv = 1.f / lst[mf];
        float iv[4];
        for (int r = 0; r < 4; ++r) iv[r] = __shfl(inv, quad * 4 + r, 16);
        for (int r = 0; r < 4; ++r) {
            int m = i0 + wid * 32 + mf * 16 + quad * 4 + r;
            for (int dt = 0; dt < 8; ++dt) {
                int d = dt * 16 + l15;
                attnT[((size_t)b * LEN + m) * 512 + h * HD + d] =
                    f2bf(oacc[mf][dt][r] * iv[r]);
            }
        }
    }
}

// ---------------------------------------------------------------------------
extern "C" void kernel_launch(void* const* d_in, const int* in_sizes, int n_in,
                              void* d_out, int out_size, void* d_ws, size_t ws_size,
                              hipStream_t stream) {
    const float* x   = (const float*)d_in[0];
    const float* gns = (const float*)d_in[1];
    const float* gnb = (const float*)d_in[2];
    const float* wq  = (const float*)d_in[3];
    const float* bq  = (const float*)d_in[4];
    const float* wk  = (const float*)d_in[5];
    const float* bk  = (const float*)d_in[6];
    const float* wv  = (const float*)d_in[7];
    const float* bv  = (const float*)d_in[8];
    const float* wo  = (const float*)d_in[9];
    const float* bo  = (const float*)d_in[10];
    float* out = (float*)d_out;

    const size_t NEL = (size_t)BATCH * CCH * LEN;   // 8388608
    float* stats = (float*)d_ws;                     // 64 floats @ 0
    u16* wcat  = (u16*)((char*)d_ws + 256);          // 4 x 512x512 bf16 weights
    u16* hT    = wcat + 4 * 262144;                  // bf16 [B,L,C]; reused as attnT
    u16* qT    = hT + NEL;
    u16* kT    = qT + NEL;
    u16* vbuf  = kT + NEL;
    u16* attnT = hT;   // hT dead after gemm<1>; alias to save 16 MB

    const u16* wq_bf = wcat;
    const u16* wk_bf = wcat + 262144;
    const u16* wv_bf = wcat + 2 * 262144;
    const u16* wo_bf = wcat + 3 * 262144;

    hipMemsetAsync(d_ws, 0, 256, stream);
    wcvt_k<<<dim3(128, 4), 256, 0, stream>>>(wq, wk, wv, wo, wcat);
    gn_stats_k<<<256, 256, 0, stream>>>(x, stats);
    gn_apply_k<<<dim3(32, 8, 8), 256, 0, stream>>>(x, gns, gnb, stats, hT);
    gemm_k<0><<<dim3(8, 16, 8), 256, 0, stream>>>(hT, wq_bf, wk_bf, bq, bk, nullptr, qT, kT);
    gemm_k<1><<<dim3(16, 4, 8), 256, 0, stream>>>(wv_bf, hT, nullptr, bv, nullptr, nullptr, vbuf, nullptr);
    attn_k<<<dim3(16, 4, 8), 256, 0, stream>>>(qT, kT, vbuf, attnT);
    gemm_k<2><<<dim3(16, 4, 8), 256, 0, stream>>>(wo_bf, attnT, nullptr, bo, nullptr, x, out, nullptr);
}

// Round 8
// 271.692 us; speedup vs baseline: 1.8479x; 1.0134x over previous
//
#include <hip/hip_runtime.h>

// ---------------------------------------------------------------------------
// AttnBlock: GroupNorm -> QKV (1x1 conv) -> 4-head attention (L=2048, hd=128)
//            -> out proj -> residual.   B=8, C=512, L=2048, G=4, NH=4.
// Storage dtype: float32. Internal compute: bf16 MFMA, f32 accumulation.
// R8: attention blocks widened to 512 threads (8 waves), each wave owns 16
//     query rows of the same 128-row Q tile -> 16 waves/CU (4/SIMD), double
//     the thread-level parallelism to overlap the serial QK->softmax->PV
//     chain (R7 showed vmcnt tuning alone is neutral at 2 waves/SIMD).
//     R7's partial-vmcnt pipeline kept (re-counted: vm<=6 / vm<=4+lgkm0).
//     GEMM/GN kernels unchanged.
// ---------------------------------------------------------------------------

typedef unsigned short u16;
typedef unsigned int   u32;
typedef unsigned long long u64;
typedef __attribute__((ext_vector_type(8)))  short          bf16x8;  // MFMA A/B frag
typedef __attribute__((ext_vector_type(4)))  float          f32x4;   // MFMA C/D frag
typedef __attribute__((ext_vector_type(4)))  unsigned int   u32x4;   // 16B copy
typedef __attribute__((ext_vector_type(8)))  unsigned short u16x8;

#define MFMA16(a, b, c) __builtin_amdgcn_mfma_f32_16x16x32_bf16((a), (b), (c), 0, 0, 0)

// s_waitcnt simm16: vmcnt[3:0] in [3:0] (+[15:14] high), expcnt[6:4], lgkmcnt[11:8]
#define WAIT_VM6         3958   // vm<=6, exp/lgkm untouched
#define WAIT_VM4_LGKM0    116   // vm<=4, lgkm=0
#define BARRIER() __builtin_amdgcn_s_barrier()

__device__ __forceinline__ u16 f2bf(float f) {
    union { float f; unsigned int i; } cv;
    cv.f = f;
    unsigned int u = cv.i;
    u += 0x7fffu + ((u >> 16) & 1);   // RNE
    return (u16)(u >> 16);
}
__device__ __forceinline__ u32 fbits(float f) {
    union { float f; unsigned int i; } cv; cv.f = f; return cv.i;
}

// async 16B global->LDS (DMA; lands at lds_base + lane*16)
__device__ __forceinline__ void async16(const u16* g, u16* l) {
    __builtin_amdgcn_global_load_lds(
        (const __attribute__((address_space(1))) unsigned int*)g,
        (__attribute__((address_space(3))) unsigned int*)l, 16, 0, 0);
}

#define BATCH 8
#define CCH   512
#define LEN   2048
#define NGRP  4
#define NHEAD 4
#define HD    128
#define GSIZE (128 * 2048)   // elements per (b, group)

// ---------------------------------------------------------------------------
// 0) Convert the four 512x512 f32 weight matrices to bf16 (once per launch).
// ---------------------------------------------------------------------------
__global__ __launch_bounds__(256) void wcvt_k(const float* __restrict__ w0,
                                              const float* __restrict__ w1,
                                              const float* __restrict__ w2,
                                              const float* __restrict__ w3,
                                              u16* __restrict__ dst) {
    const int mat = blockIdx.y;
    const float* src = (mat == 0) ? w0 : (mat == 1) ? w1 : (mat == 2) ? w2 : w3;
    const size_t base = (size_t)blockIdx.x * 2048 + (size_t)threadIdx.x * 8;
    f32x4 a = *(const f32x4*)(src + base);
    f32x4 b = *(const f32x4*)(src + base + 4);
    u16x8 o;
    for (int u = 0; u < 4; ++u) { o[u] = f2bf(a[u]); o[u + 4] = f2bf(b[u]); }
    *(u16x8*)(dst + (size_t)mat * 262144 + base) = o;
}

// ---------------------------------------------------------------------------
// 1) GroupNorm partial stats (f32 input): 256 blocks, 16 channels of one (b,g).
// ---------------------------------------------------------------------------
__global__ __launch_bounds__(256) void gn_stats_k(const float* __restrict__ x,
                                                  float* __restrict__ stats) {
    const int bid   = blockIdx.x;       // 0..255
    const int grp   = bid >> 3;         // b*4+g
    const int chunk = bid & 7;          // 16-channel slab
    const int b = grp >> 2, g = grp & 3;
    const float* base = x + ((size_t)(b * CCH + g * 128 + chunk * 16)) * LEN;

    float s = 0.f, ss = 0.f;
    for (int i = 0; i < 32; ++i) {
        int cid = threadIdx.x + i * 256;          // 0..8191 chunks of 4
        f32x4 dv = *(const f32x4*)(base + (size_t)cid * 4);
        for (int u = 0; u < 4; ++u) { s += dv[u]; ss += dv[u] * dv[u]; }
    }
    for (int m = 1; m < 64; m <<= 1) {
        s  += __shfl_xor(s,  m, 64);
        ss += __shfl_xor(ss, m, 64);
    }
    __shared__ float red[8];
    int wid = threadIdx.x >> 6, lane = threadIdx.x & 63;
    if (lane == 0) { red[wid * 2] = s; red[wid * 2 + 1] = ss; }
    __syncthreads();
    if (threadIdx.x == 0) {
        float ts  = red[0] + red[2] + red[4] + red[6];
        float tss = red[1] + red[3] + red[5] + red[7];
        atomicAdd(&stats[grp * 2],     ts);
        atomicAdd(&stats[grp * 2 + 1], tss);
    }
}

// ---------------------------------------------------------------------------
// 2) GroupNorm apply + transpose: x[b,c,l] (f32) -> hT[b,l,c] (bf16).
//    64x64 tiles through LDS.
// ---------------------------------------------------------------------------
__global__ __launch_bounds__(256) void gn_apply_k(const float* __restrict__ x,
                                                  const float* __restrict__ gns,
                                                  const float* __restrict__ gnb,
                                                  const float* __restrict__ stats,
                                                  u16* __restrict__ hT) {
    __shared__ u16 Ts[64 * 72];
    const int b = blockIdx.z, c0 = blockIdx.y * 64, l0 = blockIdx.x * 64;
    const int g = c0 >> 7;
    const int tid = threadIdx.x;

    float sum   = stats[(b * NGRP + g) * 2];
    float sumsq = stats[(b * NGRP + g) * 2 + 1];
    const float invN = 1.f / (float)GSIZE;
    float mean = sum * invN;
    float var  = sumsq * invN - mean * mean;
    float rstd = rsqrtf(var + 1e-6f);

    for (int i = 0; i < 4; ++i) {
        int cid = tid + i * 256;          // 0..1023
        int row = cid >> 4, c4 = cid & 15; // row = channel in tile, col = c4*4
        int c = c0 + row;
        float sc = gns[c] * rstd;
        float bi = gnb[c] - mean * sc;
        f32x4 dv = *(const f32x4*)(x + ((size_t)(b * CCH + c)) * LEN + l0 + c4 * 4);
        for (int u = 0; u < 4; ++u)
            Ts[row * 72 + c4 * 4 + u] = f2bf(dv[u] * sc + bi);
    }
    __syncthreads();
    for (int i = 0; i < 2; ++i) {
        int cid = tid + i * 256;          // 0..511
        int lrow = cid >> 3, c8 = cid & 7;
        u16x8 ov;
        for (int u = 0; u < 8; ++u) ov[u] = Ts[(c8 * 8 + u) * 72 + lrow];
        *(u16x8*)(hT + ((size_t)b * LEN + l0 + lrow) * CCH + c0 + c8 * 8) = ov;
    }
}

// ---------------------------------------------------------------------------
// GEMM: D[m][n] = sum_k A[m][k]*B[n][k]; operands row-major [row, 512] bf16.
// MODE 0: A=hT[b] (m=l), B=wq_bf/wk_bf (n=o, N=1024) -> qT/kT (bf16) + bias
// MODE 1: A=wv_bf (m=o), B=hT[b] (n=l) -> v[b,c,l] (bf16) + bias
// MODE 2: A=wo_bf (m=o), B=attnT[b] (n=l) -> out[b,c,l] (f32) + bias + x
// 128x128x(K=512) tiles, BK=64, 4 waves (2x2), 64 f32 acc/lane.
// Staging: double-buffered global_load_lds (issue k+1 before compute k).
// ---------------------------------------------------------------------------
template <int MODE>
__global__ __launch_bounds__(256, 2) void gemm_k(const u16* __restrict__ A0,
                                                 const u16* __restrict__ B0,
                                                 const u16* __restrict__ B1,
                                                 const float* __restrict__ bias0,
                                                 const float* __restrict__ bias1,
                                                 const float* __restrict__ resid,
                                                 void* __restrict__ out0v,
                                                 u16* __restrict__ out1) {
    __shared__ u16 As[2][128 * 64];
    __shared__ u16 Bs[2][128 * 64];
    const int b  = blockIdx.z;
    const int n0 = blockIdx.x * 128;
    const int m0 = blockIdx.y * 128;
    const int tid = threadIdx.x;
    const int lane = tid & 63, wid = tid >> 6;
    const int quad = lane >> 4, l15 = lane & 15;
    const int wm = (wid & 1) * 64, wn = (wid >> 1) * 64;

    const u16* Arow;
    if constexpr (MODE == 0) Arow = A0 + ((size_t)b * LEN + m0) * 512;
    else                     Arow = A0 + (size_t)m0 * 512;

    const u16* Brow;
    int col0 = 0;
    if constexpr (MODE == 0) {
        if (n0 < 512) { Brow = B0 + (size_t)n0 * 512;         col0 = n0; }
        else          { Brow = B1 + (size_t)(n0 - 512) * 512;  col0 = n0 - 512; }
    } else {
        Brow = B0 + ((size_t)b * LEN + n0) * 512;
    }

    f32x4 acc[4][4] = {};
    const int srl = lane >> 3, scl = lane & 7;   // 8 rows/instr, chunk lane&7

    // prologue: stage k-tile 0 into buffer 0
#pragma unroll
    for (int i = 0; i < 4; ++i) {
        int rloc = wid * 32 + i * 8 + srl;
        int lc = scl ^ (rloc & 7);
        async16(Arow + (size_t)rloc * 512 + lc * 8, &As[0][(wid * 32 + i * 8) * 64]);
        async16(Brow + (size_t)rloc * 512 + lc * 8, &Bs[0][(wid * 32 + i * 8) * 64]);
    }
    __syncthreads();

    for (int kk = 0; kk < 8; ++kk) {
        const int p = kk & 1;
        if (kk < 7) {            // issue next tile's DMA; drained by end barrier
            const int k0n = (kk + 1) * 64;
#pragma unroll
            for (int i = 0; i < 4; ++i) {
                int rloc = wid * 32 + i * 8 + srl;
                int lc = scl ^ (rloc & 7);
                async16(Arow + (size_t)rloc * 512 + k0n + lc * 8,
                        &As[1 - p][(wid * 32 + i * 8) * 64]);
                async16(Brow + (size_t)rloc * 512 + k0n + lc * 8,
                        &Bs[1 - p][(wid * 32 + i * 8) * 64]);
            }
        }
#pragma unroll
        for (int ks = 0; ks < 2; ++ks) {
            bf16x8 af[4], bfr[4];
            for (int t = 0; t < 4; ++t) {
                int ra = wm + t * 16 + l15, rb = wn + t * 16 + l15;
                af[t]  = *(const bf16x8*)(&As[p][ra * 64 + (((ks * 4 + quad) ^ (ra & 7))) * 8]);
                bfr[t] = *(const bf16x8*)(&Bs[p][rb * 64 + (((ks * 4 + quad) ^ (rb & 7))) * 8]);
            }
            for (int mt = 0; mt < 4; ++mt)
                for (int nt = 0; nt < 4; ++nt)
                    acc[mt][nt] = MFMA16(af[mt], bfr[nt], acc[mt][nt]);
        }
        __syncthreads();   // reads of [p] done; DMA(kk+1) drained (flew over MFMA)
    }

    if constexpr (MODE == 0) {
        const float* biasp = (n0 < 512) ? (bias0 + col0) : (bias1 + col0);
        u16* outp = (n0 < 512) ? (u16*)out0v : out1;
        for (int nt = 0; nt < 4; ++nt) {
            int nl = wn + nt * 16 + l15;
            float bv_ = biasp[nl];
            for (int mt = 0; mt < 4; ++mt)
                for (int r = 0; r < 4; ++r) {
                    int ml = wm + mt * 16 + quad * 4 + r;
                    size_t idx = ((size_t)b * LEN + m0 + ml) * 512 + col0 + nl;
                    outp[idx] = f2bf(acc[mt][nt][r] + bv_);
                }
        }
    } else {
        for (int mt = 0; mt < 4; ++mt)
            for (int r = 0; r < 4; ++r) {
                int ml = wm + mt * 16 + quad * 4 + r;
                float bv_ = bias0[m0 + ml];
                for (int nt = 0; nt < 4; ++nt) {
                    int nl = wn + nt * 16 + l15;
                    size_t idx = ((size_t)(b * 512 + m0 + ml)) * LEN + n0 + nl;
                    float val = acc[mt][nt][r] + bv_;
                    if constexpr (MODE == 2) {
                        ((float*)out0v)[idx] = val + resid[idx];
                    } else {
                        ((u16*)out0v)[idx] = f2bf(val);
                    }
                }
            }
    }
}

// ---------------------------------------------------------------------------
// Flash attention v7: S^T form, 64-key j-tiles, K/V LDS double-buffered,
// partial-vmcnt pipeline, 512-thread blocks (8 waves), wave owns 16 q-rows.
// Grid 512 blocks -> 2 blocks/CU -> 16 waves/CU (4/SIMD): TLP to overlap
// the serial per-wave QK->softmax->PV chain (R7 proved waits alone neutral).
// Per iter: issue K(jt+1)/V(jt+1) (2+2 DMA/thread); vm<=6 (K(jt) landed);
// barrier; QK+softmax; vm<=4+lgkm0 (V(jt) landed, QK reads retired);
// barrier; P overlays Ks[p]; PV; lgkm0; barrier. Uniform across 32 iters
// (jt=31 re-stages tile 31 harmlessly).
// ---------------------------------------------------------------------------
__global__ __launch_bounds__(512, 4) void attn_k(const u16* __restrict__ qT,
                                                 const u16* __restrict__ kT,
                                                 const u16* __restrict__ v,
                                                 u16* __restrict__ attnT) {
    __shared__ u16 Ks[2][64 * 128];   // K tile; retired buffer doubles as P[128x64]
    __shared__ u16 Vs[2][128 * 64];
    const int b = blockIdx.z, h = blockIdx.y;
    const int i0 = blockIdx.x * 128;
    const int tid = threadIdx.x, lane = tid & 63, wid = tid >> 6;  // wid 0..7
    const int quad = lane >> 4, l15 = lane & 15;
    const int mrow = wid * 16 + l15;          // this lane's q-row within tile

    // Q B-frags for this wave's 16 m-rows
    bf16x8 qa[4];
    for (int ks = 0; ks < 4; ++ks)
        qa[ks] = *(const bf16x8*)(qT + ((size_t)b * LEN + i0 + mrow) * 512 + h * HD +
                                  ks * 32 + quad * 8);

    float mst = -3.0e38f, lst = 0.f;          // per-lane (m), quad-replicated
    f32x4 oacc[8] = {};

    const float SL2E = 0.08838834764831845f * 1.4426950408889634f; // scale*log2e

    // staging geometry + loop-carried global pointers (advance one j-tile)
    // K: wave-instr covers 4 rows (lane>>4), 16 chunks/row; 2 instr/wave
    // V: wave-instr covers 8 rows (lane>>3),  8 chunks/row; 2 instr/wave
    const u16* kbase = kT + ((size_t)b * LEN) * 512 + h * HD;
    const u16* vbase = v + ((size_t)(b * CCH + h * HD)) * LEN;

    const u16* kgp[2];
    const u16* vgp[2];
    int krow[2], vrow[2];
#pragma unroll
    for (int i = 0; i < 2; ++i) {
        int rk = wid * 8 + i * 4 + (lane >> 4);
        krow[i] = wid * 8 + i * 4;
        kgp[i] = kbase + (size_t)rk * 512 + ((lane & 15) ^ (rk & 7)) * 8;
        int rv = wid * 16 + i * 8 + (lane >> 3);
        vrow[i] = wid * 16 + i * 8;
        vgp[i] = vbase + (size_t)rv * LEN + ((lane & 7) ^ (rv & 7)) * 8;
    }

    // prologue: stage tile 0 into buffer 0, advance pointers to tile 1
#pragma unroll
    for (int i = 0; i < 2; ++i) {
        async16(kgp[i], &Ks[0][krow[i] * 128]);
        async16(vgp[i], &Vs[0][vrow[i] * 64]);
        kgp[i] += 64 * 512;
        vgp[i] += 64;
    }

    for (int jt = 0; jt < 32; ++jt) {
        const int p = jt & 1;

        // issue next tile's DMA into [1-p] (jt=31: harmless re-stage of t31)
#pragma unroll
        for (int i = 0; i < 2; ++i) {
            async16(kgp[i], &Ks[1 - p][krow[i] * 128]);
            async16(vgp[i], &Vs[1 - p][vrow[i] * 64]);
        }
        if (jt < 30) {
#pragma unroll
            for (int i = 0; i < 2; ++i) { kgp[i] += 64 * 512; vgp[i] += 64; }
        }

        __builtin_amdgcn_s_waitcnt(WAIT_VM6);   // K(jt) landed (mine)
        BARRIER();                              // K(jt) landed (all waves)

        // S^T: st[jtn] rows j = jtn*16+quad*4+r, cols m = wid*16+l15
        f32x4 st[4] = {};
#pragma unroll
        for (int jtn = 0; jtn < 4; ++jtn) {
            int r = jtn * 16 + l15;
            for (int ks = 0; ks < 4; ++ks) {
                bf16x8 kf = *(const bf16x8*)(&Ks[p][r * 128 + ((ks * 4 + quad) ^ (r & 7)) * 8]);
                st[jtn] = MFMA16(kf, qa[ks], st[jtn]);
            }
        }

        // online softmax; state per lane (m), quad-replicated
        float rm = -3.0e38f;
        for (int jtn = 0; jtn < 4; ++jtn)
            for (int r = 0; r < 4; ++r) rm = fmaxf(rm, st[jtn][r]);
        rm *= SL2E;
        rm = fmaxf(rm, __shfl_xor(rm, 16, 64));
        rm = fmaxf(rm, __shfl_xor(rm, 32, 64));
        float mnew  = fmaxf(mst, rm);
        float alpha = __builtin_amdgcn_exp2f(mst - mnew);
        mst = mnew;
        float rs = 0.f;
        for (int jtn = 0; jtn < 4; ++jtn)
            for (int r = 0; r < 4; ++r) {
                float pv_ = __builtin_amdgcn_exp2f(st[jtn][r] * SL2E - mnew);
                st[jtn][r] = pv_;
                rs += pv_;
            }
        rs += __shfl_xor(rs, 16, 64);
        rs += __shfl_xor(rs, 32, 64);
        lst = lst * alpha + rs;

        // rescale O only if some lane actually changed max (late iters skip)
        if (__ballot(alpha != 1.0f) != 0ull) {
            float av[4];
            for (int r = 0; r < 4; ++r) av[r] = __shfl(alpha, quad * 4 + r, 16);
            for (int dt = 0; dt < 8; ++dt)
                for (int r = 0; r < 4; ++r) oacc[dt][r] *= av[r];
        }

        __builtin_amdgcn_s_waitcnt(WAIT_VM4_LGKM0);  // V(jt) landed; QK reads retired
        BARRIER();                                   // all waves: V ready, Ks[p] free

        // P[m][j] (bf16, half-up) overlays Ks[p] as [128][64], swizzled
        {
            int m = mrow;
#pragma unroll
            for (int jtn = 0; jtn < 4; ++jtn) {
                u64 packed =  (u64)((fbits(st[jtn][0]) + 0x8000u) >> 16)
                           | ((u64)((fbits(st[jtn][1]) + 0x8000u) >> 16) << 16)
                           | ((u64)((fbits(st[jtn][2]) + 0x8000u) >> 16) << 32)
                           | ((u64)((fbits(st[jtn][3]) + 0x8000u) >> 16) << 48);
                int pc = (jtn * 2 + (quad >> 1)) ^ (m & 7);
                *(u64*)(&Ks[p][m * 64 + pc * 8 + (quad & 1) * 4]) = packed;
            }
        }

        // PV: O[m][d] += P[m][j] * V[d][j]; own wave's P rows -> no barrier
#pragma unroll
        for (int ks = 0; ks < 2; ++ks) {
            bf16x8 pf = *(const bf16x8*)(&Ks[p][mrow * 64 + ((ks * 4 + quad) ^ (mrow & 7)) * 8]);
            for (int dt = 0; dt < 8; ++dt) {
                int d = dt * 16 + l15;
                bf16x8 vf = *(const bf16x8*)(&Vs[p][d * 64 + ((ks * 4 + quad) ^ (d & 7)) * 8]);
                oacc[dt] = MFMA16(pf, vf, oacc[dt]);
            }
        }

        __builtin_amdgcn_s_waitcnt(WAIT_VM4_LGKM0);  // DS retired; prefetch stays out
        BARRIER();                                   // PV done before [p] restage
    }

    float inv = 1.f / lst;
    float iv[4];
    for (int r = 0; r < 4; ++r) iv[r] = __shfl(inv, quad * 4 + r, 16);
    for (int r = 0; r < 4; ++r) {
        int m = i0 + wid * 16 + quad * 4 + r;
        for (int dt = 0; dt < 8; ++dt) {
            int d = dt * 16 + l15;
            attnT[((size_t)b * LEN + m) * 512 + h * HD + d] = f2bf(oacc[dt][r] * iv[r]);
        }
    }
}

// ---------------------------------------------------------------------------
extern "C" void kernel_launch(void* const* d_in, const int* in_sizes, int n_in,
                              void* d_out, int out_size, void* d_ws, size_t ws_size,
                              hipStream_t stream) {
    const float* x   = (const float*)d_in[0];
    const float* gns = (const float*)d_in[1];
    const float* gnb = (const float*)d_in[2];
    const float* wq  = (const float*)d_in[3];
    const float* bq  = (const float*)d_in[4];
    const float* wk  = (const float*)d_in[5];
    const float* bk  = (const float*)d_in[6];
    const float* wv  = (const float*)d_in[7];
    const float* bv  = (const float*)d_in[8];
    const float* wo  = (const float*)d_in[9];
    const float* bo  = (const float*)d_in[10];
    float* out = (float*)d_out;

    const size_t NEL = (size_t)BATCH * CCH * LEN;   // 8388608
    float* stats = (float*)d_ws;                     // 64 floats @ 0
    u16* wcat  = (u16*)((char*)d_ws + 256);          // 4 x 512x512 bf16 weights
    u16* hT    = wcat + 4 * 262144;                  // bf16 [B,L,C]; reused as attnT
    u16* qT    = hT + NEL;
    u16* kT    = qT + NEL;
    u16* vbuf  = kT + NEL;
    u16* attnT = hT;   // hT dead after gemm<1>; alias to save 16 MB

    const u16* wq_bf = wcat;
    const u16* wk_bf = wcat + 262144;
    const u16* wv_bf = wcat + 2 * 262144;
    const u16* wo_bf = wcat + 3 * 262144;

    hipMemsetAsync(d_ws, 0, 256, stream);
    wcvt_k<<<dim3(128, 4), 256, 0, stream>>>(wq, wk, wv, wo, wcat);
    gn_stats_k<<<256, 256, 0, stream>>>(x, stats);
    gn_apply_k<<<dim3(32, 8, 8), 256, 0, stream>>>(x, gns, gnb, stats, hT);
    gemm_k<0><<<dim3(8, 16, 8), 256, 0, stream>>>(hT, wq_bf, wk_bf, bq, bk, nullptr, qT, kT);
    gemm_k<1><<<dim3(16, 4, 8), 256, 0, stream>>>(wv_bf, hT, nullptr, bv, nullptr, nullptr, vbuf, nullptr);
    attn_k<<<dim3(16, 4, 8), 512, 0, stream>>>(qT, kT, vbuf, attnT);
    gemm_k<2><<<dim3(16, 4, 8), 256, 0, stream>>>(wo_bf, attnT, nullptr, bo, nullptr, x, out, nullptr);
}